// Round 1
// baseline (8627.483 us; speedup 1.0000x reference)
//
#include <hip/hip_runtime.h>
#include <hip/hip_bf16.h>
#include <math.h>

// xLSTM block stack: 8 sequential blocks, then post-LN + projection.
// Round 0: correctness-first fp32 implementation.
//
// Dims
#define SB   64            // batch
#define SS   46            // seq
#define SE   1024          // embed
#define SI   2048          // inner
#define ROWS (SB*SS)       // 2944
#define NHH  4             // mLSTM heads
#define DHH  512           // head dim
#define NHQ_ 512           // headwise 4x4 heads
#define OUTD 512

// ---------------------------------------------------------------------------
// LayerNorm (no bias): out[row] = (x-mu)*rsqrt(var+1e-5)*w
__global__ __launch_bounds__(256) void ln_kernel(
    const float* __restrict__ x, size_t row_stride,
    const float* __restrict__ w, float* __restrict__ out, int ncols) {
  const float* xr = x + (size_t)blockIdx.x * row_stride;
  float s1 = 0.f, s2 = 0.f;
  for (int i = threadIdx.x; i < ncols; i += 256) { float v = xr[i]; s1 += v; s2 += v*v; }
  __shared__ float r1[4], r2[4];
  for (int off = 32; off; off >>= 1) { s1 += __shfl_down(s1, off); s2 += __shfl_down(s2, off); }
  if ((threadIdx.x & 63) == 0) { r1[threadIdx.x >> 6] = s1; r2[threadIdx.x >> 6] = s2; }
  __syncthreads();
  s1 = r1[0]+r1[1]+r1[2]+r1[3];
  s2 = r2[0]+r2[1]+r2[2]+r2[3];
  const float invn = 1.f / (float)ncols;
  const float mu = s1 * invn;
  const float var = s2 * invn - mu*mu;
  const float rs = rsqrtf(var + 1e-5f);
  float* orow = out + (size_t)blockIdx.x * ncols;
  for (int i = threadIdx.x; i < ncols; i += 256) orow[i] = (xr[i]-mu)*rs*w[i];
}

// ---------------------------------------------------------------------------
// fp32 GEMM: C[M,N] (+)= A[M,K] * B[K,N].  128x128 tile, 8x8 per thread.
// M,N implied by grid (exact multiples of 128). K multiple of 8.
__global__ __launch_bounds__(256) void gemm128(
    const float* __restrict__ A, size_t lda,
    const float* __restrict__ B, size_t ldb,
    float* __restrict__ C, size_t ldc,
    int K, int accum) {
  __shared__ float As[8][132];
  __shared__ float Bs[8][132];
  const int tx = threadIdx.x & 15;   // col group
  const int ty = threadIdx.x >> 4;   // row group
  const int row0 = blockIdx.y * 128;
  const int col0 = blockIdx.x * 128;
  float acc[8][8];
  for (int i = 0; i < 8; ++i) for (int j = 0; j < 8; ++j) acc[i][j] = 0.f;

  const int lm  = threadIdx.x >> 1;        // A row 0..127
  const int lkq = (threadIdx.x & 1) * 4;   // A k sub 0/4
  const int lkk = threadIdx.x >> 5;        // B k 0..7
  const int ln4 = (threadIdx.x & 31) * 4;  // B col sub

  for (int k0 = 0; k0 < K; k0 += 8) {
    float4 a4 = *(const float4*)(A + (size_t)(row0 + lm)*lda + k0 + lkq);
    As[lkq+0][lm] = a4.x; As[lkq+1][lm] = a4.y; As[lkq+2][lm] = a4.z; As[lkq+3][lm] = a4.w;
    *(float4*)(&Bs[lkk][ln4]) = *(const float4*)(B + (size_t)(k0 + lkk)*ldb + col0 + ln4);
    __syncthreads();
#pragma unroll
    for (int kk = 0; kk < 8; ++kk) {
      float4 av0 = *(const float4*)&As[kk][ty*8];
      float4 av1 = *(const float4*)&As[kk][ty*8+4];
      float4 bv0 = *(const float4*)&Bs[kk][tx*8];
      float4 bv1 = *(const float4*)&Bs[kk][tx*8+4];
      const float a[8] = {av0.x,av0.y,av0.z,av0.w,av1.x,av1.y,av1.z,av1.w};
      const float b[8] = {bv0.x,bv0.y,bv0.z,bv0.w,bv1.x,bv1.y,bv1.z,bv1.w};
#pragma unroll
      for (int i = 0; i < 8; ++i)
#pragma unroll
        for (int j = 0; j < 8; ++j) acc[i][j] += a[i]*b[j];
    }
    __syncthreads();
  }
  const int r0 = row0 + ty*8;
  const int c0 = col0 + tx*8;
  for (int i = 0; i < 8; ++i) {
    float* crow = C + (size_t)(r0 + i)*ldc + c0;
    if (accum) { for (int j = 0; j < 8; ++j) crow[j] += acc[i][j]; }
    else       { for (int j = 0; j < 8; ++j) crow[j]  = acc[i][j]; }
  }
}

// ---------------------------------------------------------------------------
// Causal depthwise conv (K=4) + bias + SiLU.  in = up cols [0,2048), stride 4096.
__global__ __launch_bounds__(256) void conv_silu_kernel(
    const float* __restrict__ up, const float* __restrict__ cw,
    const float* __restrict__ cb, float* __restrict__ xact) {
  const int idx = blockIdx.x * 256 + threadIdx.x;
  if (idx >= ROWS * SI) return;
  const int row = idx >> 11;          // b*46+s
  const int c   = idx & (SI - 1);
  const int s   = row % SS;
  float acc = cb[c];
  const float* w4 = cw + (size_t)c * 4;
#pragma unroll
  for (int j = 0; j < 4; ++j) {
    const int ss = s - 3 + j;
    if (ss >= 0) acc += up[(size_t)(row - 3 + j) * (2*SI) + c] * w4[j];
  }
  xact[(size_t)row * SI + c] = acc / (1.f + expf(-acc));
}

// ---------------------------------------------------------------------------
// Headwise 4x4 projections: q,k from x_act; v from x_in (up cols [0,2048)).
// qkv row layout: [q(2048) | k(2048) | v(2048)]
__global__ __launch_bounds__(256) void headwise_kernel(
    const float* __restrict__ up, const float* __restrict__ xact,
    const float* __restrict__ wq, const float* __restrict__ wk,
    const float* __restrict__ wv, float* __restrict__ qkv) {
  const int idx = blockIdx.x * 256 + threadIdx.x;
  if (idx >= ROWS * SI) return;
  const int row = idx >> 11;
  const int c   = idx & (SI - 1);
  const int hq  = c >> 2;
  const int o   = c & 3;
  const float* xa = xact + (size_t)row * SI     + hq*4;
  const float* xi = up   + (size_t)row * (2*SI) + hq*4;
  const size_t wo = ((size_t)hq*4 + o)*4;
  const float* wq4 = wq + wo;
  const float* wk4 = wk + wo;
  const float* wv4 = wv + wo;
  float q = 0.f, k = 0.f, v = 0.f;
#pragma unroll
  for (int d = 0; d < 4; ++d) {
    q += xa[d]*wq4[d]; k += xa[d]*wk4[d]; v += xi[d]*wv4[d];
  }
  float* orow = qkv + (size_t)row * (3*SI);
  orow[c] = q; orow[SI + c] = k; orow[2*SI + c] = v;
}

// ---------------------------------------------------------------------------
// Gate pre-activations: ipre/fpre[b,h,s] = gate_in[b,s,:] . w[:,h] + bias[h]
__global__ __launch_bounds__(256) void gate_kernel(
    const float* __restrict__ qkv,
    const float* __restrict__ igw, const float* __restrict__ igb,
    const float* __restrict__ fgw, const float* __restrict__ fgb,
    float* __restrict__ ipre, float* __restrict__ fpre) {
  const int row = blockIdx.x;
  const int b = row / SS, s = row - b*SS;
  const float* g = qkv + (size_t)row * (3*SI);
  float aI[4] = {0,0,0,0}, aF[4] = {0,0,0,0};
  for (int d = threadIdx.x; d < 3*SI; d += 256) {
    const float gv = g[d];
    const float4 wi = *(const float4*)(igw + (size_t)d*4);
    const float4 wf = *(const float4*)(fgw + (size_t)d*4);
    aI[0] += gv*wi.x; aI[1] += gv*wi.y; aI[2] += gv*wi.z; aI[3] += gv*wi.w;
    aF[0] += gv*wf.x; aF[1] += gv*wf.y; aF[2] += gv*wf.z; aF[3] += gv*wf.w;
  }
  __shared__ float rI[4][4], rF[4][4];
  for (int off = 32; off; off >>= 1)
    for (int h = 0; h < 4; ++h) { aI[h] += __shfl_down(aI[h], off); aF[h] += __shfl_down(aF[h], off); }
  if ((threadIdx.x & 63) == 0)
    for (int h = 0; h < 4; ++h) { rI[h][threadIdx.x >> 6] = aI[h]; rF[h][threadIdx.x >> 6] = aF[h]; }
  __syncthreads();
  if (threadIdx.x < 8) {
    const int h = threadIdx.x & 3;
    const bool isF = threadIdx.x >= 4;
    const float* rr = isF ? &rF[h][0] : &rI[h][0];
    const float v = rr[0]+rr[1]+rr[2]+rr[3] + (isF ? fgb[h] : igb[h]);
    float* dst = isF ? fpre : ipre;
    dst[((size_t)b*NHH + h)*SS + s] = v;
  }
}

// ---------------------------------------------------------------------------
// mLSTM per (b,head): stabilized parallel form; writes h into q region of qkv.
__global__ __launch_bounds__(256) void mlstm_kernel(
    float* __restrict__ qkv,
    const float* __restrict__ ipre, const float* __restrict__ fpre) {
  const int bh = blockIdx.x;
  const int b = bh >> 2, h = bh & 3;
  __shared__ float cum[SS], mm[SS], inv[SS], ips[SS];
  __shared__ float Cs[SS][SS + 2];
  const float* ip = ipre + (size_t)bh * SS;
  const float* fp = fpre + (size_t)bh * SS;
  if (threadIdx.x < SS) ips[threadIdx.x] = ip[threadIdx.x];
  __syncthreads();
  if (threadIdx.x == 0) {
    float c = 0.f, rmax = -INFINITY;
    for (int s = 0; s < SS; ++s) {
      const float xv = fp[s];
      const float lf = fminf(xv, 0.f) - log1pf(expf(-fabsf(xv)));  // log_sigmoid
      c += lf; cum[s] = c;
      const float e = ips[s] - c;
      rmax = fmaxf(rmax, e);
      mm[s] = c + rmax;   // m[t] = cum[t] + max_{s<=t}(ipre[s]-cum[s])
    }
  }
  __syncthreads();
  const float rsq = 0.04419417382415922f;  // 512^-0.5
  for (int p = threadIdx.x; p < SS*SS; p += 256) {
    const int t = p / SS, s = p - t*SS;
    float val = 0.f;
    if (s <= t) {
      const float4* q4 = (const float4*)(qkv + (size_t)(b*SS + t)*(3*SI) + h*DHH);
      const float4* k4 = (const float4*)(qkv + (size_t)(b*SS + s)*(3*SI) + SI + h*DHH);
      float dot = 0.f;
      for (int d = 0; d < DHH/4; ++d) {
        const float4 qa = q4[d], ka = k4[d];
        dot += qa.x*ka.x + qa.y*ka.y + qa.z*ka.z + qa.w*ka.w;
      }
      val = dot * rsq * expf(cum[t] - cum[s] + ips[s] - mm[t]);
    }
    Cs[t][s] = val;
  }
  __syncthreads();
  if (threadIdx.x < SS) {
    const int t = threadIdx.x;
    float sum = 0.f;
    for (int s = 0; s <= t; ++s) sum += Cs[t][s];
    inv[t] = 1.f / (fmaxf(fabsf(sum), expf(-mm[t])) + 1e-6f);
  }
  __syncthreads();
  for (int idx = threadIdx.x; idx < SS*DHH; idx += 256) {
    const int t = idx >> 9, d = idx & (DHH-1);
    const float* vb = qkv + (size_t)(b*SS)*(3*SI) + 2*SI + h*DHH + d;
    float acc = 0.f;
    for (int s = 0; s <= t; ++s) acc += Cs[t][s] * vb[(size_t)s*(3*SI)];
    qkv[(size_t)(b*SS + t)*(3*SI) + h*DHH + d] = acc * inv[t];
  }
}

// ---------------------------------------------------------------------------
// Per-(b,s,head) LN over DH, * mhn_w, + skip*x_act, * silu(z). In-place in q region.
__global__ __launch_bounds__(256) void mhnorm_kernel(
    float* __restrict__ qkv, const float* __restrict__ xact,
    const float* __restrict__ up, const float* __restrict__ skip,
    const float* __restrict__ mhn) {
  const int bs = blockIdx.x >> 2;
  const int h  = blockIdx.x & 3;
  float* hrow = qkv + (size_t)bs * (3*SI) + h*DHH;
  const float v0 = hrow[threadIdx.x], v1 = hrow[threadIdx.x + 256];
  float s1 = v0 + v1, s2 = v0*v0 + v1*v1;
  __shared__ float r1[4], r2[4];
  for (int off = 32; off; off >>= 1) { s1 += __shfl_down(s1, off); s2 += __shfl_down(s2, off); }
  if ((threadIdx.x & 63) == 0) { r1[threadIdx.x >> 6] = s1; r2[threadIdx.x >> 6] = s2; }
  __syncthreads();
  s1 = r1[0]+r1[1]+r1[2]+r1[3];
  s2 = r2[0]+r2[1]+r2[2]+r2[3];
  const float mu = s1 * (1.f/512.f);
  const float var = s2 * (1.f/512.f) - mu*mu;
  const float rs = rsqrtf(var + 1e-5f);
  const float vv[2] = {v0, v1};
#pragma unroll
  for (int ii = 0; ii < 2; ++ii) {
    const int i = threadIdx.x + ii*256;
    const int c = h*DHH + i;
    const float hv = (vv[ii]-mu)*rs*mhn[c] + skip[c]*xact[(size_t)bs*SI + c];
    const float zv = up[(size_t)bs*(2*SI) + SI + c];
    hrow[i] = hv * (zv / (1.f + expf(-zv)));
  }
}

// ---------------------------------------------------------------------------
// Final projection: out[b,o] = lastln[b,:] . proj_w[:,o] + proj_b[o]
__global__ __launch_bounds__(256) void proj_kernel(
    const float* __restrict__ lastln, const float* __restrict__ pw,
    const float* __restrict__ pb, float* __restrict__ out) {
  const int b = blockIdx.x;
  __shared__ float xs[SE];
  for (int i = threadIdx.x; i < SE; i += 256) xs[i] = lastln[(size_t)b*SE + i];
  __syncthreads();
  for (int o = threadIdx.x; o < OUTD; o += 256) {
    float acc = pb[o];
    for (int k = 0; k < SE; ++k) acc += xs[k] * pw[(size_t)k*OUTD + o];
    out[(size_t)b*OUTD + o] = acc;
  }
}

// ---------------------------------------------------------------------------
extern "C" void kernel_launch(void* const* d_in, const int* in_sizes, int n_in,
                              void* d_out, int out_size, void* d_ws, size_t ws_size,
                              hipStream_t stream) {
  const float* x_in   = (const float*)d_in[0];
  const float* ln_w   = (const float*)d_in[1];
  const float* w_up   = (const float*)d_in[2];
  const float* conv_w = (const float*)d_in[3];
  const float* conv_b = (const float*)d_in[4];
  const float* wq     = (const float*)d_in[5];
  const float* wk     = (const float*)d_in[6];
  const float* wv     = (const float*)d_in[7];
  const float* ig_w   = (const float*)d_in[8];
  const float* ig_b   = (const float*)d_in[9];
  const float* fg_w   = (const float*)d_in[10];
  const float* fg_b   = (const float*)d_in[11];
  const float* skip   = (const float*)d_in[12];
  const float* mhn_w  = (const float*)d_in[13];
  const float* w_down = (const float*)d_in[14];
  const float* post_w = (const float*)d_in[15];
  const float* proj_w = (const float*)d_in[16];
  const float* proj_b = (const float*)d_in[17];
  float* out = (float*)d_out;

  float* ws = (float*)d_ws;
  float* xbuf   = ws;                                  // ROWS*SE
  float* lnbuf  = xbuf  + (size_t)ROWS*SE;             // ROWS*SE
  float* upbuf  = lnbuf + (size_t)ROWS*SE;             // ROWS*2*SI (x_in | z)
  float* xact   = upbuf + (size_t)ROWS*2*SI;           // ROWS*SI
  float* qkv    = xact  + (size_t)ROWS*SI;             // ROWS*3*SI (q|k|v, h overwrites q)
  float* ipre   = qkv   + (size_t)ROWS*3*SI;           // B*NH*S
  float* fpre   = ipre  + (size_t)SB*NHH*SS;
  float* lastln = fpre  + (size_t)SB*NHH*SS;           // B*SE

  hipMemcpyAsync(xbuf, x_in, (size_t)ROWS*SE*sizeof(float),
                 hipMemcpyDeviceToDevice, stream);

  for (int blk = 0; blk < 8; ++blk) {
    const float* lw   = ln_w   + (size_t)blk*SE;
    const float* wu   = w_up   + (size_t)blk*SE*2*SI;
    const float* cw   = conv_w + (size_t)blk*SI*4;
    const float* cb   = conv_b + (size_t)blk*SI;
    const float* wqb  = wq     + (size_t)blk*NHQ_*16;
    const float* wkb  = wk     + (size_t)blk*NHQ_*16;
    const float* wvb  = wv     + (size_t)blk*NHQ_*16;
    const float* igwb = ig_w   + (size_t)blk*3*SI*NHH;
    const float* igbb = ig_b   + (size_t)blk*NHH;
    const float* fgwb = fg_w   + (size_t)blk*3*SI*NHH;
    const float* fgbb = fg_b   + (size_t)blk*NHH;
    const float* skb  = skip   + (size_t)blk*SI;
    const float* mhb  = mhn_w  + (size_t)blk*SI;
    const float* wdb  = w_down + (size_t)blk*SI*SE;

    ln_kernel<<<ROWS, 256, 0, stream>>>(xbuf, SE, lw, lnbuf, SE);
    gemm128<<<dim3(32, 23), 256, 0, stream>>>(lnbuf, SE, wu, 2*SI, upbuf, 2*SI, SE, 0);
    conv_silu_kernel<<<(ROWS*SI)/256, 256, 0, stream>>>(upbuf, cw, cb, xact);
    headwise_kernel<<<(ROWS*SI)/256, 256, 0, stream>>>(upbuf, xact, wqb, wkb, wvb, qkv);
    gate_kernel<<<ROWS, 256, 0, stream>>>(qkv, igwb, igbb, fgwb, fgbb, ipre, fpre);
    mlstm_kernel<<<SB*NHH, 256, 0, stream>>>(qkv, ipre, fpre);
    mhnorm_kernel<<<ROWS*NHH, 256, 0, stream>>>(qkv, xact, upbuf, skb, mhb);
    gemm128<<<dim3(8, 23), 256, 0, stream>>>(qkv, 3*SI, wdb, SE, xbuf, SE, SI, 1);
  }
  // post-LN on last token of each batch, then projection
  ln_kernel<<<SB, 256, 0, stream>>>(xbuf + (size_t)(SS-1)*SE, (size_t)SS*SE, post_w, lastln, SE);
  proj_kernel<<<SB, 256, 0, stream>>>(lastln, proj_w, proj_b, out);
}

// Round 2
// 4076.448 us; speedup vs baseline: 2.1164x; 2.1164x over previous
//
#include <hip/hip_runtime.h>
#include <hip/hip_bf16.h>
#include <math.h>

// xLSTM block stack: 8 sequential blocks, then post-LN + projection.
// Round 1: big GEMMs -> bf16 MFMA (m97-style 128x128 tile, global_load_lds).
//
#define SB   64            // batch
#define SS   46            // seq
#define SE   1024          // embed
#define SI   2048          // inner
#define ROWS (SB*SS)       // 2944
#define NHH  4             // mLSTM heads
#define DHH  512           // head dim
#define NHQ_ 512           // headwise 4x4 heads
#define OUTD 512

typedef __attribute__((ext_vector_type(8))) short bf16x8;
typedef __attribute__((ext_vector_type(4))) float f32x4;

__device__ __forceinline__ void gload_lds16(const void* g, void* lds) {
  __builtin_amdgcn_global_load_lds(
      (const __attribute__((address_space(1))) unsigned int*)g,
      (__attribute__((address_space(3))) unsigned int*)lds, 16, 0, 0);
}

// ---------------------------------------------------------------------------
// LayerNorm -> bf16 out: out[row] = bf16((x-mu)*rsqrt(var+1e-5)*w)
__global__ __launch_bounds__(256) void ln_bf16_kernel(
    const float* __restrict__ x, size_t row_stride,
    const float* __restrict__ w, __hip_bfloat16* __restrict__ out, int ncols) {
  const float* xr = x + (size_t)blockIdx.x * row_stride;
  float s1 = 0.f, s2 = 0.f;
  for (int i = threadIdx.x; i < ncols; i += 256) { float v = xr[i]; s1 += v; s2 += v*v; }
  __shared__ float r1[4], r2[4];
  for (int off = 32; off; off >>= 1) { s1 += __shfl_down(s1, off); s2 += __shfl_down(s2, off); }
  if ((threadIdx.x & 63) == 0) { r1[threadIdx.x >> 6] = s1; r2[threadIdx.x >> 6] = s2; }
  __syncthreads();
  s1 = r1[0]+r1[1]+r1[2]+r1[3];
  s2 = r2[0]+r2[1]+r2[2]+r2[3];
  const float invn = 1.f / (float)ncols;
  const float mu = s1 * invn;
  const float var = s2 * invn - mu*mu;
  const float rs = rsqrtf(var + 1e-5f);
  __hip_bfloat16* orow = out + (size_t)blockIdx.x * ncols;
  for (int i = threadIdx.x; i < ncols; i += 256)
    orow[i] = __float2bfloat16((xr[i]-mu)*rs*w[i]);
}

// LayerNorm fp32 out (post-LN before projection)
__global__ __launch_bounds__(256) void ln_kernel(
    const float* __restrict__ x, size_t row_stride,
    const float* __restrict__ w, float* __restrict__ out, int ncols) {
  const float* xr = x + (size_t)blockIdx.x * row_stride;
  float s1 = 0.f, s2 = 0.f;
  for (int i = threadIdx.x; i < ncols; i += 256) { float v = xr[i]; s1 += v; s2 += v*v; }
  __shared__ float r1[4], r2[4];
  for (int off = 32; off; off >>= 1) { s1 += __shfl_down(s1, off); s2 += __shfl_down(s2, off); }
  if ((threadIdx.x & 63) == 0) { r1[threadIdx.x >> 6] = s1; r2[threadIdx.x >> 6] = s2; }
  __syncthreads();
  s1 = r1[0]+r1[1]+r1[2]+r1[3];
  s2 = r2[0]+r2[1]+r2[2]+r2[3];
  const float invn = 1.f / (float)ncols;
  const float mu = s1 * invn;
  const float var = s2 * invn - mu*mu;
  const float rs = rsqrtf(var + 1e-5f);
  float* orow = out + (size_t)blockIdx.x * ncols;
  for (int i = threadIdx.x; i < ncols; i += 256) orow[i] = (xr[i]-mu)*rs*w[i];
}

// ---------------------------------------------------------------------------
// Transpose + convert: W [K][N] fp32 -> Wt [N][K] bf16.  32x32 tiles.
__global__ __launch_bounds__(256) void transpose_bf16_kernel(
    const float* __restrict__ W, __hip_bfloat16* __restrict__ Wt, int K, int N) {
  __shared__ float tile[32][33];
  const int k0 = blockIdx.y * 32, n0 = blockIdx.x * 32;
  const int tr = threadIdx.x >> 5;   // 0..7
  const int tc = threadIdx.x & 31;
#pragma unroll
  for (int i = 0; i < 4; ++i)
    tile[tr + i*8][tc] = W[(size_t)(k0 + tr + i*8)*N + n0 + tc];
  __syncthreads();
#pragma unroll
  for (int i = 0; i < 4; ++i)
    Wt[(size_t)(n0 + tr + i*8)*K + k0 + tc] = __float2bfloat16(tile[tc][tr + i*8]);
}

// ---------------------------------------------------------------------------
// bf16 MFMA GEMM: C[M,N] (+)= A[M,K] * Bt[N,K]^T.  128x128 tile, BK=32,
// 4 waves (2x2), each 64x64 via 4x4 fragments of 16x16x32.
__global__ __launch_bounds__(256) void gemm_mfma(
    const __hip_bfloat16* __restrict__ A, int lda,
    const __hip_bfloat16* __restrict__ Bt, int ldb,
    float* __restrict__ C, int ldc, int K, int accum) {
  __shared__ short As[128*32];
  __shared__ short Bs[128*32];
  const int t = threadIdx.x;
  const int lane = t & 63;
  const int w = t >> 6;
  const int wr = w >> 1, wc = w & 1;
  const int l15 = lane & 15, lg = lane >> 4;
  const int row0 = blockIdx.y * 128, col0 = blockIdx.x * 128;
  f32x4 acc[4][4];
#pragma unroll
  for (int m = 0; m < 4; ++m)
#pragma unroll
    for (int n = 0; n < 4; ++n) acc[m][n] = (f32x4){0.f,0.f,0.f,0.f};

  for (int k0 = 0; k0 < K; k0 += 32) {
#pragma unroll
    for (int c = 0; c < 2; ++c) {
      const int L  = c*4096 + t*16;     // byte offset within 8KB tile
      const int r  = L >> 6;            // tile row (64B per row of 32 bf16)
      const int kk = (L & 63) >> 1;     // bf16 offset within row
      gload_lds16(A  + (size_t)(row0 + r)*lda + k0 + kk, (char*)As + L);
      gload_lds16(Bt + (size_t)(col0 + r)*ldb + k0 + kk, (char*)Bs + L);
    }
    __syncthreads();
    bf16x8 af[4], bfr[4];
#pragma unroll
    for (int m = 0; m < 4; ++m)
      af[m] = *(const bf16x8*)&As[(wr*64 + m*16 + l15)*32 + lg*8];
#pragma unroll
    for (int n = 0; n < 4; ++n)
      bfr[n] = *(const bf16x8*)&Bs[(wc*64 + n*16 + l15)*32 + lg*8];
#pragma unroll
    for (int m = 0; m < 4; ++m)
#pragma unroll
      for (int n = 0; n < 4; ++n)
        acc[m][n] = __builtin_amdgcn_mfma_f32_16x16x32_bf16(af[m], bfr[n], acc[m][n], 0, 0, 0);
    __syncthreads();
  }
#pragma unroll
  for (int m = 0; m < 4; ++m) {
#pragma unroll
    for (int n = 0; n < 4; ++n) {
      const int cc = col0 + wc*64 + n*16 + l15;
#pragma unroll
      for (int j = 0; j < 4; ++j) {
        const int rr = row0 + wr*64 + m*16 + lg*4 + j;
        float* p = C + (size_t)rr*ldc + cc;
        if (accum) *p += acc[m][n][j]; else *p = acc[m][n][j];
      }
    }
  }
}

// ---------------------------------------------------------------------------
// Causal depthwise conv (K=4) + bias + SiLU.  in = up cols [0,2048), stride 4096.
__global__ __launch_bounds__(256) void conv_silu_kernel(
    const float* __restrict__ up, const float* __restrict__ cw,
    const float* __restrict__ cb, float* __restrict__ xact) {
  const int idx = blockIdx.x * 256 + threadIdx.x;
  if (idx >= ROWS * SI) return;
  const int row = idx >> 11;          // b*46+s
  const int c   = idx & (SI - 1);
  const int s   = row % SS;
  float acc = cb[c];
  const float* w4 = cw + (size_t)c * 4;
#pragma unroll
  for (int j = 0; j < 4; ++j) {
    const int ss = s - 3 + j;
    if (ss >= 0) acc += up[(size_t)(row - 3 + j) * (2*SI) + c] * w4[j];
  }
  xact[(size_t)row * SI + c] = acc / (1.f + expf(-acc));
}

// ---------------------------------------------------------------------------
// Headwise 4x4 projections: q,k from x_act; v from x_in (up cols [0,2048)).
__global__ __launch_bounds__(256) void headwise_kernel(
    const float* __restrict__ up, const float* __restrict__ xact,
    const float* __restrict__ wq, const float* __restrict__ wk,
    const float* __restrict__ wv, float* __restrict__ qkv) {
  const int idx = blockIdx.x * 256 + threadIdx.x;
  if (idx >= ROWS * SI) return;
  const int row = idx >> 11;
  const int c   = idx & (SI - 1);
  const int hq  = c >> 2;
  const int o   = c & 3;
  const float* xa = xact + (size_t)row * SI     + hq*4;
  const float* xi = up   + (size_t)row * (2*SI) + hq*4;
  const size_t wo = ((size_t)hq*4 + o)*4;
  const float* wq4 = wq + wo;
  const float* wk4 = wk + wo;
  const float* wv4 = wv + wo;
  float q = 0.f, k = 0.f, v = 0.f;
#pragma unroll
  for (int d = 0; d < 4; ++d) {
    q += xa[d]*wq4[d]; k += xa[d]*wk4[d]; v += xi[d]*wv4[d];
  }
  float* orow = qkv + (size_t)row * (3*SI);
  orow[c] = q; orow[SI + c] = k; orow[2*SI + c] = v;
}

// ---------------------------------------------------------------------------
// Gate pre-activations: ipre/fpre[b,h,s] = gate_in[b,s,:] . w[:,h] + bias[h]
__global__ __launch_bounds__(256) void gate_kernel(
    const float* __restrict__ qkv,
    const float* __restrict__ igw, const float* __restrict__ igb,
    const float* __restrict__ fgw, const float* __restrict__ fgb,
    float* __restrict__ ipre, float* __restrict__ fpre) {
  const int row = blockIdx.x;
  const int b = row / SS, s = row - b*SS;
  const float* g = qkv + (size_t)row * (3*SI);
  float aI[4] = {0,0,0,0}, aF[4] = {0,0,0,0};
  for (int d = threadIdx.x; d < 3*SI; d += 256) {
    const float gv = g[d];
    const float4 wi = *(const float4*)(igw + (size_t)d*4);
    const float4 wf = *(const float4*)(fgw + (size_t)d*4);
    aI[0] += gv*wi.x; aI[1] += gv*wi.y; aI[2] += gv*wi.z; aI[3] += gv*wi.w;
    aF[0] += gv*wf.x; aF[1] += gv*wf.y; aF[2] += gv*wf.z; aF[3] += gv*wf.w;
  }
  __shared__ float rI[4][4], rF[4][4];
  for (int off = 32; off; off >>= 1)
    for (int h = 0; h < 4; ++h) { aI[h] += __shfl_down(aI[h], off); aF[h] += __shfl_down(aF[h], off); }
  if ((threadIdx.x & 63) == 0)
    for (int h = 0; h < 4; ++h) { rI[h][threadIdx.x >> 6] = aI[h]; rF[h][threadIdx.x >> 6] = aF[h]; }
  __syncthreads();
  if (threadIdx.x < 8) {
    const int h = threadIdx.x & 3;
    const bool isF = threadIdx.x >= 4;
    const float* rr = isF ? &rF[h][0] : &rI[h][0];
    const float v = rr[0]+rr[1]+rr[2]+rr[3] + (isF ? fgb[h] : igb[h]);
    float* dst = isF ? fpre : ipre;
    dst[((size_t)b*NHH + h)*SS + s] = v;
  }
}

// ---------------------------------------------------------------------------
// mLSTM per (b,head): stabilized parallel form; writes h into q region of qkv.
__global__ __launch_bounds__(256) void mlstm_kernel(
    float* __restrict__ qkv,
    const float* __restrict__ ipre, const float* __restrict__ fpre) {
  const int bh = blockIdx.x;
  const int b = bh >> 2, h = bh & 3;
  __shared__ float cum[SS], mm[SS], inv[SS], ips[SS];
  __shared__ float Cs[SS][SS + 2];
  const float* ip = ipre + (size_t)bh * SS;
  const float* fp = fpre + (size_t)bh * SS;
  if (threadIdx.x < SS) ips[threadIdx.x] = ip[threadIdx.x];
  __syncthreads();
  if (threadIdx.x == 0) {
    float c = 0.f, rmax = -INFINITY;
    for (int s = 0; s < SS; ++s) {
      const float xv = fp[s];
      const float lf = fminf(xv, 0.f) - log1pf(expf(-fabsf(xv)));  // log_sigmoid
      c += lf; cum[s] = c;
      const float e = ips[s] - c;
      rmax = fmaxf(rmax, e);
      mm[s] = c + rmax;   // m[t] = cum[t] + max_{s<=t}(ipre[s]-cum[s])
    }
  }
  __syncthreads();
  const float rsq = 0.04419417382415922f;  // 512^-0.5
  for (int p = threadIdx.x; p < SS*SS; p += 256) {
    const int t = p / SS, s = p - t*SS;
    float val = 0.f;
    if (s <= t) {
      const float4* q4 = (const float4*)(qkv + (size_t)(b*SS + t)*(3*SI) + h*DHH);
      const float4* k4 = (const float4*)(qkv + (size_t)(b*SS + s)*(3*SI) + SI + h*DHH);
      float dot = 0.f;
      for (int d = 0; d < DHH/4; ++d) {
        const float4 qa = q4[d], ka = k4[d];
        dot += qa.x*ka.x + qa.y*ka.y + qa.z*ka.z + qa.w*ka.w;
      }
      val = dot * rsq * expf(cum[t] - cum[s] + ips[s] - mm[t]);
    }
    Cs[t][s] = val;
  }
  __syncthreads();
  if (threadIdx.x < SS) {
    const int t = threadIdx.x;
    float sum = 0.f;
    for (int s = 0; s <= t; ++s) sum += Cs[t][s];
    inv[t] = 1.f / (fmaxf(fabsf(sum), expf(-mm[t])) + 1e-6f);
  }
  __syncthreads();
  for (int idx = threadIdx.x; idx < SS*DHH; idx += 256) {
    const int t = idx >> 9, d = idx & (DHH-1);
    const float* vb = qkv + (size_t)(b*SS)*(3*SI) + 2*SI + h*DHH + d;
    float acc = 0.f;
    for (int s = 0; s <= t; ++s) acc += Cs[t][s] * vb[(size_t)s*(3*SI)];
    qkv[(size_t)(b*SS + t)*(3*SI) + h*DHH + d] = acc * inv[t];
  }
}

// ---------------------------------------------------------------------------
// Per-(b,s,head) LN over DH, * mhn_w, + skip*x_act, * silu(z) -> bf16 habf.
__global__ __launch_bounds__(256) void mhnorm_kernel(
    const float* __restrict__ qkv, const float* __restrict__ xact,
    const float* __restrict__ up, const float* __restrict__ skip,
    const float* __restrict__ mhn, __hip_bfloat16* __restrict__ habf) {
  const int bs = blockIdx.x >> 2;
  const int h  = blockIdx.x & 3;
  const float* hrow = qkv + (size_t)bs * (3*SI) + h*DHH;
  const float v0 = hrow[threadIdx.x], v1 = hrow[threadIdx.x + 256];
  float s1 = v0 + v1, s2 = v0*v0 + v1*v1;
  __shared__ float r1[4], r2[4];
  for (int off = 32; off; off >>= 1) { s1 += __shfl_down(s1, off); s2 += __shfl_down(s2, off); }
  if ((threadIdx.x & 63) == 0) { r1[threadIdx.x >> 6] = s1; r2[threadIdx.x >> 6] = s2; }
  __syncthreads();
  s1 = r1[0]+r1[1]+r1[2]+r1[3];
  s2 = r2[0]+r2[1]+r2[2]+r2[3];
  const float mu = s1 * (1.f/512.f);
  const float var = s2 * (1.f/512.f) - mu*mu;
  const float rs = rsqrtf(var + 1e-5f);
  const float vv[2] = {v0, v1};
#pragma unroll
  for (int ii = 0; ii < 2; ++ii) {
    const int i = threadIdx.x + ii*256;
    const int c = h*DHH + i;
    const float hv = (vv[ii]-mu)*rs*mhn[c] + skip[c]*xact[(size_t)bs*SI + c];
    const float zv = up[(size_t)bs*(2*SI) + SI + c];
    habf[(size_t)bs*SI + c] = __float2bfloat16(hv * (zv / (1.f + expf(-zv))));
  }
}

// ---------------------------------------------------------------------------
// Final projection: out[b,o] = lastln[b,:] . proj_w[:,o] + proj_b[o]
__global__ __launch_bounds__(256) void proj_kernel(
    const float* __restrict__ lastln, const float* __restrict__ pw,
    const float* __restrict__ pb, float* __restrict__ out) {
  const int b = blockIdx.x;
  __shared__ float xs[SE];
  for (int i = threadIdx.x; i < SE; i += 256) xs[i] = lastln[(size_t)b*SE + i];
  __syncthreads();
  for (int o = threadIdx.x; o < OUTD; o += 256) {
    float acc = pb[o];
    for (int k = 0; k < SE; ++k) acc += xs[k] * pw[(size_t)k*OUTD + o];
    out[(size_t)b*OUTD + o] = acc;
  }
}

// ---------------------------------------------------------------------------
extern "C" void kernel_launch(void* const* d_in, const int* in_sizes, int n_in,
                              void* d_out, int out_size, void* d_ws, size_t ws_size,
                              hipStream_t stream) {
  const float* x_in   = (const float*)d_in[0];
  const float* ln_w   = (const float*)d_in[1];
  const float* w_up   = (const float*)d_in[2];
  const float* conv_w = (const float*)d_in[3];
  const float* conv_b = (const float*)d_in[4];
  const float* wq     = (const float*)d_in[5];
  const float* wk     = (const float*)d_in[6];
  const float* wv     = (const float*)d_in[7];
  const float* ig_w   = (const float*)d_in[8];
  const float* ig_b   = (const float*)d_in[9];
  const float* fg_w   = (const float*)d_in[10];
  const float* fg_b   = (const float*)d_in[11];
  const float* skip   = (const float*)d_in[12];
  const float* mhn_w  = (const float*)d_in[13];
  const float* w_down = (const float*)d_in[14];
  const float* post_w = (const float*)d_in[15];
  const float* proj_w = (const float*)d_in[16];
  const float* proj_b = (const float*)d_in[17];
  float* out = (float*)d_out;

  float* ws = (float*)d_ws;
  float* xbuf   = ws;                                   // ROWS*SE fp32
  float* upbuf  = xbuf  + (size_t)ROWS*SE;              // ROWS*2*SI fp32
  float* xact   = upbuf + (size_t)ROWS*2*SI;            // ROWS*SI fp32
  float* qkv    = xact  + (size_t)ROWS*SI;              // ROWS*3*SI fp32
  float* ipre   = qkv   + (size_t)ROWS*3*SI;            // B*NH*S
  float* fpre   = ipre  + (size_t)SB*NHH*SS;
  float* lastln = fpre  + (size_t)SB*NHH*SS;            // B*SE
  __hip_bfloat16* lnb  = (__hip_bfloat16*)(lastln + (size_t)SB*SE); // ROWS*SE bf16
  __hip_bfloat16* habf = (__hip_bfloat16*)((float*)lnb + (size_t)ROWS*SE/2); // ROWS*SI bf16
  __hip_bfloat16* wT   = (__hip_bfloat16*)((float*)habf + (size_t)ROWS*SI/2); // max 4096*1024 bf16

  hipMemcpyAsync(xbuf, x_in, (size_t)ROWS*SE*sizeof(float),
                 hipMemcpyDeviceToDevice, stream);

  for (int blk = 0; blk < 8; ++blk) {
    const float* lw   = ln_w   + (size_t)blk*SE;
    const float* wu   = w_up   + (size_t)blk*SE*2*SI;
    const float* cw   = conv_w + (size_t)blk*SI*4;
    const float* cb   = conv_b + (size_t)blk*SI;
    const float* wqb  = wq     + (size_t)blk*NHQ_*16;
    const float* wkb  = wk     + (size_t)blk*NHQ_*16;
    const float* wvb  = wv     + (size_t)blk*NHQ_*16;
    const float* igwb = ig_w   + (size_t)blk*3*SI*NHH;
    const float* igbb = ig_b   + (size_t)blk*NHH;
    const float* fgwb = fg_w   + (size_t)blk*3*SI*NHH;
    const float* fgbb = fg_b   + (size_t)blk*NHH;
    const float* skb  = skip   + (size_t)blk*SI;
    const float* mhb  = mhn_w  + (size_t)blk*SI;
    const float* wdb  = w_down + (size_t)blk*SI*SE;

    // w_up [1024][4096] -> wT [4096][1024] bf16
    transpose_bf16_kernel<<<dim3(128, 32), 256, 0, stream>>>(wu, wT, SE, 2*SI);
    ln_bf16_kernel<<<ROWS, 256, 0, stream>>>(xbuf, SE, lw, lnb, SE);
    // up: [2944,1024] x [1024,4096]
    gemm_mfma<<<dim3(32, 23), 256, 0, stream>>>(lnb, SE, wT, SE, upbuf, 2*SI, SE, 0);
    conv_silu_kernel<<<(ROWS*SI)/256, 256, 0, stream>>>(upbuf, cw, cb, xact);
    headwise_kernel<<<(ROWS*SI)/256, 256, 0, stream>>>(upbuf, xact, wqb, wkb, wvb, qkv);
    gate_kernel<<<ROWS, 256, 0, stream>>>(qkv, igwb, igbb, fgwb, fgbb, ipre, fpre);
    mlstm_kernel<<<SB*NHH, 256, 0, stream>>>(qkv, ipre, fpre);
    mhnorm_kernel<<<ROWS*NHH, 256, 0, stream>>>(qkv, xact, upbuf, skb, mhb, habf);
    // w_down [2048][1024] -> wT [1024][2048] bf16
    transpose_bf16_kernel<<<dim3(32, 64), 256, 0, stream>>>(wdb, wT, SI, SE);
    // down: [2944,2048] x [2048,1024] accumulate into residual
    gemm_mfma<<<dim3(8, 23), 256, 0, stream>>>(habf, SI, wT, SI, xbuf, SE, SI, 1);
  }
  // post-LN on last token of each batch, then projection
  ln_kernel<<<SB, 256, 0, stream>>>(xbuf + (size_t)(SS-1)*SE, (size_t)SS*SE, post_w, lastln, SE);
  proj_kernel<<<SB, 256, 0, stream>>>(lastln, proj_w, proj_b, out);
}

// Round 3
// 2746.803 us; speedup vs baseline: 3.1409x; 1.4841x over previous
//
#include <hip/hip_runtime.h>
#include <hip/hip_bf16.h>
#include <math.h>

// xLSTM block stack: 8 sequential blocks, then post-LN + projection.
// Round 2: mlstm -> MFMA mini-attention per (b,head); bf16 q/k/v buffers.
//
#define SB   64            // batch
#define SS   46            // seq
#define SE   1024          // embed
#define SI   2048          // inner
#define ROWS (SB*SS)       // 2944
#define NHH  4             // mLSTM heads
#define DHH  512           // head dim
#define NHQ_ 512           // headwise 4x4 heads
#define OUTD 512

typedef __attribute__((ext_vector_type(8))) short bf16x8;
typedef __attribute__((ext_vector_type(4))) float f32x4;

__device__ __forceinline__ void gload_lds16(const void* g, void* lds) {
  __builtin_amdgcn_global_load_lds(
      (const __attribute__((address_space(1))) unsigned int*)g,
      (__attribute__((address_space(3))) unsigned int*)lds, 16, 0, 0);
}

__device__ __forceinline__ float bf2f(short s) {
  union { unsigned int u; float f; } x;
  x.u = ((unsigned int)(unsigned short)s) << 16;
  return x.f;
}

// ---------------------------------------------------------------------------
// LayerNorm -> bf16 out
__global__ __launch_bounds__(256) void ln_bf16_kernel(
    const float* __restrict__ x, size_t row_stride,
    const float* __restrict__ w, __hip_bfloat16* __restrict__ out, int ncols) {
  const float* xr = x + (size_t)blockIdx.x * row_stride;
  float s1 = 0.f, s2 = 0.f;
  for (int i = threadIdx.x; i < ncols; i += 256) { float v = xr[i]; s1 += v; s2 += v*v; }
  __shared__ float r1[4], r2[4];
  for (int off = 32; off; off >>= 1) { s1 += __shfl_down(s1, off); s2 += __shfl_down(s2, off); }
  if ((threadIdx.x & 63) == 0) { r1[threadIdx.x >> 6] = s1; r2[threadIdx.x >> 6] = s2; }
  __syncthreads();
  s1 = r1[0]+r1[1]+r1[2]+r1[3];
  s2 = r2[0]+r2[1]+r2[2]+r2[3];
  const float invn = 1.f / (float)ncols;
  const float mu = s1 * invn;
  const float var = s2 * invn - mu*mu;
  const float rs = rsqrtf(var + 1e-5f);
  __hip_bfloat16* orow = out + (size_t)blockIdx.x * ncols;
  for (int i = threadIdx.x; i < ncols; i += 256)
    orow[i] = __float2bfloat16((xr[i]-mu)*rs*w[i]);
}

// LayerNorm fp32 out (post-LN before projection)
__global__ __launch_bounds__(256) void ln_kernel(
    const float* __restrict__ x, size_t row_stride,
    const float* __restrict__ w, float* __restrict__ out, int ncols) {
  const float* xr = x + (size_t)blockIdx.x * row_stride;
  float s1 = 0.f, s2 = 0.f;
  for (int i = threadIdx.x; i < ncols; i += 256) { float v = xr[i]; s1 += v; s2 += v*v; }
  __shared__ float r1[4], r2[4];
  for (int off = 32; off; off >>= 1) { s1 += __shfl_down(s1, off); s2 += __shfl_down(s2, off); }
  if ((threadIdx.x & 63) == 0) { r1[threadIdx.x >> 6] = s1; r2[threadIdx.x >> 6] = s2; }
  __syncthreads();
  s1 = r1[0]+r1[1]+r1[2]+r1[3];
  s2 = r2[0]+r2[1]+r2[2]+r2[3];
  const float invn = 1.f / (float)ncols;
  const float mu = s1 * invn;
  const float var = s2 * invn - mu*mu;
  const float rs = rsqrtf(var + 1e-5f);
  float* orow = out + (size_t)blockIdx.x * ncols;
  for (int i = threadIdx.x; i < ncols; i += 256) orow[i] = (xr[i]-mu)*rs*w[i];
}

// ---------------------------------------------------------------------------
// Transpose + convert: W [K][N] fp32 -> Wt [N][K] bf16.  32x32 tiles.
__global__ __launch_bounds__(256) void transpose_bf16_kernel(
    const float* __restrict__ W, __hip_bfloat16* __restrict__ Wt, int K, int N) {
  __shared__ float tile[32][33];
  const int k0 = blockIdx.y * 32, n0 = blockIdx.x * 32;
  const int tr = threadIdx.x >> 5;
  const int tc = threadIdx.x & 31;
#pragma unroll
  for (int i = 0; i < 4; ++i)
    tile[tr + i*8][tc] = W[(size_t)(k0 + tr + i*8)*N + n0 + tc];
  __syncthreads();
#pragma unroll
  for (int i = 0; i < 4; ++i)
    Wt[(size_t)(n0 + tr + i*8)*K + k0 + tc] = __float2bfloat16(tile[tc][tr + i*8]);
}

// ---------------------------------------------------------------------------
// bf16 MFMA GEMM: C[M,N] (+)= A[M,K] * Bt[N,K]^T.  128x128 tile, BK=32.
__global__ __launch_bounds__(256) void gemm_mfma(
    const __hip_bfloat16* __restrict__ A, int lda,
    const __hip_bfloat16* __restrict__ Bt, int ldb,
    float* __restrict__ C, int ldc, int K, int accum) {
  __shared__ short As[128*32];
  __shared__ short Bs[128*32];
  const int t = threadIdx.x;
  const int lane = t & 63;
  const int w = t >> 6;
  const int wr = w >> 1, wc = w & 1;
  const int l15 = lane & 15, lg = lane >> 4;
  const int row0 = blockIdx.y * 128, col0 = blockIdx.x * 128;
  f32x4 acc[4][4];
#pragma unroll
  for (int m = 0; m < 4; ++m)
#pragma unroll
    for (int n = 0; n < 4; ++n) acc[m][n] = (f32x4){0.f,0.f,0.f,0.f};

  for (int k0 = 0; k0 < K; k0 += 32) {
#pragma unroll
    for (int c = 0; c < 2; ++c) {
      const int L  = c*4096 + t*16;
      const int r  = L >> 6;
      const int kk = (L & 63) >> 1;
      gload_lds16(A  + (size_t)(row0 + r)*lda + k0 + kk, (char*)As + L);
      gload_lds16(Bt + (size_t)(col0 + r)*ldb + k0 + kk, (char*)Bs + L);
    }
    __syncthreads();
    bf16x8 af[4], bfr[4];
#pragma unroll
    for (int m = 0; m < 4; ++m)
      af[m] = *(const bf16x8*)&As[(wr*64 + m*16 + l15)*32 + lg*8];
#pragma unroll
    for (int n = 0; n < 4; ++n)
      bfr[n] = *(const bf16x8*)&Bs[(wc*64 + n*16 + l15)*32 + lg*8];
#pragma unroll
    for (int m = 0; m < 4; ++m)
#pragma unroll
      for (int n = 0; n < 4; ++n)
        acc[m][n] = __builtin_amdgcn_mfma_f32_16x16x32_bf16(af[m], bfr[n], acc[m][n], 0, 0, 0);
    __syncthreads();
  }
#pragma unroll
  for (int m = 0; m < 4; ++m) {
#pragma unroll
    for (int n = 0; n < 4; ++n) {
      const int cc = col0 + wc*64 + n*16 + l15;
#pragma unroll
      for (int j = 0; j < 4; ++j) {
        const int rr = row0 + wr*64 + m*16 + lg*4 + j;
        float* p = C + (size_t)rr*ldc + cc;
        if (accum) *p += acc[m][n][j]; else *p = acc[m][n][j];
      }
    }
  }
}

// ---------------------------------------------------------------------------
// Causal depthwise conv (K=4) + bias + SiLU.
__global__ __launch_bounds__(256) void conv_silu_kernel(
    const float* __restrict__ up, const float* __restrict__ cw,
    const float* __restrict__ cb, float* __restrict__ xact) {
  const int idx = blockIdx.x * 256 + threadIdx.x;
  if (idx >= ROWS * SI) return;
  const int row = idx >> 11;
  const int c   = idx & (SI - 1);
  const int s   = row % SS;
  float acc = cb[c];
  const float* w4 = cw + (size_t)c * 4;
#pragma unroll
  for (int j = 0; j < 4; ++j) {
    const int ss = s - 3 + j;
    if (ss >= 0) acc += up[(size_t)(row - 3 + j) * (2*SI) + c] * w4[j];
  }
  xact[(size_t)row * SI + c] = acc / (1.f + expf(-acc));
}

// ---------------------------------------------------------------------------
// Headwise 4x4 projections -> bf16 q/k/v in [b][h][s][d] head-contiguous layout.
__global__ __launch_bounds__(256) void headwise_kernel(
    const float* __restrict__ up, const float* __restrict__ xact,
    const float* __restrict__ wq, const float* __restrict__ wk,
    const float* __restrict__ wv,
    __hip_bfloat16* __restrict__ qb, __hip_bfloat16* __restrict__ kb,
    __hip_bfloat16* __restrict__ vb) {
  const int idx = blockIdx.x * 256 + threadIdx.x;
  if (idx >= ROWS * SI) return;
  const int row = idx >> 11;
  const int c   = idx & (SI - 1);
  const int hq  = c >> 2;
  const int o   = c & 3;
  const float* xa = xact + (size_t)row * SI     + hq*4;
  const float* xi = up   + (size_t)row * (2*SI) + hq*4;
  const size_t wo = ((size_t)hq*4 + o)*4;
  const float* wq4 = wq + wo;
  const float* wk4 = wk + wo;
  const float* wv4 = wv + wo;
  float q = 0.f, k = 0.f, v = 0.f;
#pragma unroll
  for (int d = 0; d < 4; ++d) {
    q += xa[d]*wq4[d]; k += xa[d]*wk4[d]; v += xi[d]*wv4[d];
  }
  const int b = row / SS, s = row - (row / SS) * SS;
  const int h = c >> 9, dd = c & 511;
  const size_t dst = (((size_t)b*NHH + h)*SS + s)*DHH + dd;
  qb[dst] = __float2bfloat16(q);
  kb[dst] = __float2bfloat16(k);
  vb[dst] = __float2bfloat16(v);
}

// ---------------------------------------------------------------------------
// Gate pre-activations from bf16 q/k/v: ipre/fpre[b,h,s]
__global__ __launch_bounds__(256) void gate_kernel(
    const __hip_bfloat16* __restrict__ qb, const __hip_bfloat16* __restrict__ kb,
    const __hip_bfloat16* __restrict__ vb,
    const float* __restrict__ igw, const float* __restrict__ igb,
    const float* __restrict__ fgw, const float* __restrict__ fgb,
    float* __restrict__ ipre, float* __restrict__ fpre) {
  const int row = blockIdx.x;
  const int b = row / SS, s = row - b*SS;
  float aI[4] = {0,0,0,0}, aF[4] = {0,0,0,0};
  for (int c8 = threadIdx.x; c8 < 768; c8 += 256) {
    const int c0 = c8 * 8;                 // gate_in channel base
    const int part = c0 >> 11;             // 0:q 1:k 2:v
    const int cc = c0 & 2047;
    const int h = cc >> 9, dd = cc & 511;
    const __hip_bfloat16* src = part == 0 ? qb : (part == 1 ? kb : vb);
    const bf16x8 g8 = *(const bf16x8*)(src + (((size_t)b*NHH + h)*SS + s)*DHH + dd);
#pragma unroll
    for (int j = 0; j < 8; ++j) {
      const float gv = bf2f(g8[j]);
      const float4 wi = *(const float4*)(igw + (size_t)(c0+j)*4);
      const float4 wf = *(const float4*)(fgw + (size_t)(c0+j)*4);
      aI[0] += gv*wi.x; aI[1] += gv*wi.y; aI[2] += gv*wi.z; aI[3] += gv*wi.w;
      aF[0] += gv*wf.x; aF[1] += gv*wf.y; aF[2] += gv*wf.z; aF[3] += gv*wf.w;
    }
  }
  __shared__ float rI[4][4], rF[4][4];
  for (int off = 32; off; off >>= 1)
    for (int h = 0; h < 4; ++h) { aI[h] += __shfl_down(aI[h], off); aF[h] += __shfl_down(aF[h], off); }
  if ((threadIdx.x & 63) == 0)
    for (int h = 0; h < 4; ++h) { rI[h][threadIdx.x >> 6] = aI[h]; rF[h][threadIdx.x >> 6] = aF[h]; }
  __syncthreads();
  if (threadIdx.x < 8) {
    const int h = threadIdx.x & 3;
    const bool isF = threadIdx.x >= 4;
    const float* rr = isF ? &rF[h][0] : &rI[h][0];
    const float v = rr[0]+rr[1]+rr[2]+rr[3] + (isF ? fgb[h] : igb[h]);
    float* dst = isF ? fpre : ipre;
    dst[((size_t)b*NHH + h)*SS + s] = v;
  }
}

// ---------------------------------------------------------------------------
// mLSTM per (b,head), MFMA QK^T + VALU PV.  h -> hbuf [b][h][s][d] fp32.
__global__ __launch_bounds__(256) void mlstm_mfma_kernel(
    const __hip_bfloat16* __restrict__ qb, const __hip_bfloat16* __restrict__ kb,
    const __hip_bfloat16* __restrict__ vb,
    const float* __restrict__ ipre, const float* __restrict__ fpre,
    float* __restrict__ hbuf) {
  const int bh = blockIdx.x;                 // b*4 + h
  const int t = threadIdx.x;
  const int lane = t & 63, wid = t >> 6;
  const int l15 = lane & 15, lg = lane >> 4;

  __shared__ short QKs[2][48*264];           // Q/K half-D tiles [48][264], pad 264
  __shared__ float Cs[46][48];
  __shared__ float cum[46], mmv[46], ips[46], fps[46], inv[46];
  short* Vs = &QKs[0][0];                    // alias: V [46][520] bf16 (47840B <= 50688B)

  if (t < SS) { ips[t] = ipre[bh*SS + t]; fps[t] = fpre[bh*SS + t]; }

  // wave -> (mt,nt) tile pairs of the 3x3 QK^T tiling
  int prs[3]; int np = 0;
  for (int p = wid; p < 9; p += 4) prs[np++] = p;
  f32x4 acc[3];
#pragma unroll
  for (int i = 0; i < 3; ++i) acc[i] = (f32x4){0.f,0.f,0.f,0.f};

  for (int ph = 0; ph < 2; ++ph) {
    __syncthreads();                          // prev-phase reads done; ips/fps visible
    for (int i = t; i < 48*32; i += 256) {
      const int row = i >> 5, oc = i & 31;
      bf16x8 vq = {0,0,0,0,0,0,0,0}, vk = {0,0,0,0,0,0,0,0};
      if (row < SS) {
        const size_t src = ((size_t)bh*SS + row)*DHH + ph*256 + oc*8;
        vq = *(const bf16x8*)(qb + src);
        vk = *(const bf16x8*)(kb + src);
      }
      *(bf16x8*)&QKs[0][row*264 + oc*8] = vq;
      *(bf16x8*)&QKs[1][row*264 + oc*8] = vk;
    }
    __syncthreads();
#pragma unroll
    for (int kc = 0; kc < 8; ++kc) {
      for (int i = 0; i < np; ++i) {
        const int mt = prs[i] / 3, nt = prs[i] - 3*(prs[i]/3);
        const bf16x8 a = *(const bf16x8*)&QKs[0][(mt*16 + l15)*264 + kc*32 + lg*8];
        const bf16x8 b = *(const bf16x8*)&QKs[1][(nt*16 + l15)*264 + kc*32 + lg*8];
        acc[i] = __builtin_amdgcn_mfma_f32_16x16x32_bf16(a, b, acc[i], 0, 0, 0);
      }
    }
  }
  __syncthreads();                            // MFMA LDS reads done
  // serial log-sigmoid scan (thread 0): cum, m
  if (t == 0) {
    float c = 0.f, rmax = -INFINITY;
    for (int s = 0; s < SS; ++s) {
      const float xv = fps[s];
      const float lf = fminf(xv, 0.f) - log1pf(expf(-fabsf(xv)));
      c += lf; cum[s] = c;
      rmax = fmaxf(rmax, ips[s] - c);
      mmv[s] = c + rmax;
    }
  }
  // stage V (overwrites QK LDS)
  for (int i = t; i < SS*64; i += 256) {
    const int row = i >> 6, oc = i & 63;
    *(bf16x8*)&Vs[row*520 + oc*8] =
        *(const bf16x8*)(vb + ((size_t)bh*SS + row)*DHH + oc*8);
  }
  __syncthreads();                            // scan + V staged
  // D-weight + mask, write Cs
  const float rsq = 0.04419417382415922f;     // 512^-0.5
  for (int i = 0; i < np; ++i) {
    const int mt = prs[i] / 3, nt = prs[i] - 3*(prs[i]/3);
    const int s = nt*16 + l15;
    if (s < SS) {
#pragma unroll
      for (int j = 0; j < 4; ++j) {
        const int tt = mt*16 + lg*4 + j;
        if (tt < SS) {
          float wgt = 0.f;
          if (s <= tt) wgt = rsq * expf(cum[tt] - cum[s] + ips[s] - mmv[tt]);
          Cs[tt][s] = acc[i][j] * wgt;
        }
      }
    }
  }
  __syncthreads();
  if (t < SS) {
    float ssum = 0.f;
    for (int s = 0; s <= t; ++s) ssum += Cs[t][s];
    inv[t] = 1.f / (fmaxf(fabsf(ssum), expf(-mmv[t])) + 1e-6f);
  }
  __syncthreads();
  // PV: H[t][d] = sum_s Cs[t][s] * V[s][d];  wave wid owns t in {wid, wid+4, ...}
  for (int it = 0; it < 12; ++it) {
    const int tt = wid + it*4;
    if (tt >= SS) break;
    float a[8];
#pragma unroll
    for (int j = 0; j < 8; ++j) a[j] = 0.f;
    for (int s = 0; s <= tt; ++s) {
      const float c = Cs[tt][s];              // broadcast within wave
      const bf16x8 v8 = *(const bf16x8*)&Vs[s*520 + lane*8];
#pragma unroll
      for (int j = 0; j < 8; ++j) a[j] += c * bf2f(v8[j]);
    }
    const float sc = inv[tt];
    float* dst = hbuf + ((size_t)bh*SS + tt)*DHH + lane*8;
    float4 o0 = {a[0]*sc, a[1]*sc, a[2]*sc, a[3]*sc};
    float4 o1 = {a[4]*sc, a[5]*sc, a[6]*sc, a[7]*sc};
    *(float4*)dst = o0;
    *(float4*)(dst + 4) = o1;
  }
}

// ---------------------------------------------------------------------------
// Per-(b,s,head) LN over DH from hbuf, * mhn_w, + skip*x_act, * silu(z) -> bf16.
__global__ __launch_bounds__(256) void mhnorm_kernel(
    const float* __restrict__ hbuf, const float* __restrict__ xact,
    const float* __restrict__ up, const float* __restrict__ skip,
    const float* __restrict__ mhn, __hip_bfloat16* __restrict__ habf) {
  const int bs = blockIdx.x >> 2;
  const int h  = blockIdx.x & 3;
  const int b = bs / SS, s = bs - b*SS;
  const float* hrow = hbuf + (((size_t)b*NHH + h)*SS + s)*DHH;
  const float v0 = hrow[threadIdx.x], v1 = hrow[threadIdx.x + 256];
  float s1 = v0 + v1, s2 = v0*v0 + v1*v1;
  __shared__ float r1[4], r2[4];
  for (int off = 32; off; off >>= 1) { s1 += __shfl_down(s1, off); s2 += __shfl_down(s2, off); }
  if ((threadIdx.x & 63) == 0) { r1[threadIdx.x >> 6] = s1; r2[threadIdx.x >> 6] = s2; }
  __syncthreads();
  s1 = r1[0]+r1[1]+r1[2]+r1[3];
  s2 = r2[0]+r2[1]+r2[2]+r2[3];
  const float mu = s1 * (1.f/512.f);
  const float var = s2 * (1.f/512.f) - mu*mu;
  const float rs = rsqrtf(var + 1e-5f);
  const float vv[2] = {v0, v1};
#pragma unroll
  for (int ii = 0; ii < 2; ++ii) {
    const int i = threadIdx.x + ii*256;
    const int c = h*DHH + i;
    const float hv = (vv[ii]-mu)*rs*mhn[c] + skip[c]*xact[(size_t)bs*SI + c];
    const float zv = up[(size_t)bs*(2*SI) + SI + c];
    habf[(size_t)bs*SI + c] = __float2bfloat16(hv * (zv / (1.f + expf(-zv))));
  }
}

// ---------------------------------------------------------------------------
// Final projection
__global__ __launch_bounds__(256) void proj_kernel(
    const float* __restrict__ lastln, const float* __restrict__ pw,
    const float* __restrict__ pb, float* __restrict__ out) {
  const int b = blockIdx.x;
  __shared__ float xs[SE];
  for (int i = threadIdx.x; i < SE; i += 256) xs[i] = lastln[(size_t)b*SE + i];
  __syncthreads();
  for (int o = threadIdx.x; o < OUTD; o += 256) {
    float acc = pb[o];
    for (int k = 0; k < SE; ++k) acc += xs[k] * pw[(size_t)k*OUTD + o];
    out[(size_t)b*OUTD + o] = acc;
  }
}

// ---------------------------------------------------------------------------
extern "C" void kernel_launch(void* const* d_in, const int* in_sizes, int n_in,
                              void* d_out, int out_size, void* d_ws, size_t ws_size,
                              hipStream_t stream) {
  const float* x_in   = (const float*)d_in[0];
  const float* ln_w   = (const float*)d_in[1];
  const float* w_up   = (const float*)d_in[2];
  const float* conv_w = (const float*)d_in[3];
  const float* conv_b = (const float*)d_in[4];
  const float* wq     = (const float*)d_in[5];
  const float* wk     = (const float*)d_in[6];
  const float* wv     = (const float*)d_in[7];
  const float* ig_w   = (const float*)d_in[8];
  const float* ig_b   = (const float*)d_in[9];
  const float* fg_w   = (const float*)d_in[10];
  const float* fg_b   = (const float*)d_in[11];
  const float* skip   = (const float*)d_in[12];
  const float* mhn_w  = (const float*)d_in[13];
  const float* w_down = (const float*)d_in[14];
  const float* post_w = (const float*)d_in[15];
  const float* proj_w = (const float*)d_in[16];
  const float* proj_b = (const float*)d_in[17];
  float* out = (float*)d_out;

  float* ws = (float*)d_ws;
  float* xbuf   = ws;                                   // ROWS*SE
  float* upbuf  = xbuf  + (size_t)ROWS*SE;              // ROWS*2*SI
  float* xact   = upbuf + (size_t)ROWS*2*SI;            // ROWS*SI
  float* hbuf   = xact  + (size_t)ROWS*SI;              // ROWS*SI ([b][h][s][d])
  float* ipre   = hbuf  + (size_t)ROWS*SI;              // B*NH*S
  float* fpre   = ipre  + (size_t)SB*NHH*SS;
  float* lastln = fpre  + (size_t)SB*NHH*SS;            // B*SE
  __hip_bfloat16* lnb  = (__hip_bfloat16*)(lastln + (size_t)SB*SE);          // ROWS*SE
  __hip_bfloat16* qb   = lnb  + (size_t)ROWS*SE;        // ROWS*SI each, [b][h][s][d]
  __hip_bfloat16* kb   = qb   + (size_t)ROWS*SI;
  __hip_bfloat16* vb   = kb   + (size_t)ROWS*SI;
  __hip_bfloat16* habf = vb   + (size_t)ROWS*SI;        // ROWS*SI
  __hip_bfloat16* wT   = habf + (size_t)ROWS*SI;        // 4096*1024

  hipMemcpyAsync(xbuf, x_in, (size_t)ROWS*SE*sizeof(float),
                 hipMemcpyDeviceToDevice, stream);

  for (int blk = 0; blk < 8; ++blk) {
    const float* lw   = ln_w   + (size_t)blk*SE;
    const float* wu   = w_up   + (size_t)blk*SE*2*SI;
    const float* cw   = conv_w + (size_t)blk*SI*4;
    const float* cb   = conv_b + (size_t)blk*SI;
    const float* wqb  = wq     + (size_t)blk*NHQ_*16;
    const float* wkb  = wk     + (size_t)blk*NHQ_*16;
    const float* wvb  = wv     + (size_t)blk*NHQ_*16;
    const float* igwb = ig_w   + (size_t)blk*3*SI*NHH;
    const float* igbb = ig_b   + (size_t)blk*NHH;
    const float* fgwb = fg_w   + (size_t)blk*3*SI*NHH;
    const float* fgbb = fg_b   + (size_t)blk*NHH;
    const float* skb  = skip   + (size_t)blk*SI;
    const float* mhb  = mhn_w  + (size_t)blk*SI;
    const float* wdb  = w_down + (size_t)blk*SI*SE;

    transpose_bf16_kernel<<<dim3(128, 32), 256, 0, stream>>>(wu, wT, SE, 2*SI);
    ln_bf16_kernel<<<ROWS, 256, 0, stream>>>(xbuf, SE, lw, lnb, SE);
    gemm_mfma<<<dim3(32, 23), 256, 0, stream>>>(lnb, SE, wT, SE, upbuf, 2*SI, SE, 0);
    conv_silu_kernel<<<(ROWS*SI)/256, 256, 0, stream>>>(upbuf, cw, cb, xact);
    headwise_kernel<<<(ROWS*SI)/256, 256, 0, stream>>>(upbuf, xact, wqb, wkb, wvb, qb, kb, vb);
    gate_kernel<<<ROWS, 256, 0, stream>>>(qb, kb, vb, igwb, igbb, fgwb, fgbb, ipre, fpre);
    mlstm_mfma_kernel<<<SB*NHH, 256, 0, stream>>>(qb, kb, vb, ipre, fpre, hbuf);
    mhnorm_kernel<<<ROWS*NHH, 256, 0, stream>>>(hbuf, xact, upbuf, skb, mhb, habf);
    transpose_bf16_kernel<<<dim3(32, 64), 256, 0, stream>>>(wdb, wT, SI, SE);
    gemm_mfma<<<dim3(8, 23), 256, 0, stream>>>(habf, SI, wT, SI, xbuf, SE, SI, 1);
  }
  ln_kernel<<<SB, 256, 0, stream>>>(xbuf + (size_t)(SS-1)*SE, (size_t)SS*SE, post_w, lastln, SE);
  proj_kernel<<<SB, 256, 0, stream>>>(lastln, proj_w, proj_b, out);
}

// Round 4
// 2020.314 us; speedup vs baseline: 4.2704x; 1.3596x over previous
//
#include <hip/hip_runtime.h>
#include <hip/hip_bf16.h>
#include <math.h>

// xLSTM block stack: 8 sequential blocks, then post-LN + projection.
// Round 3: fuse conv+silu+headwise+gate-partials into one kernel;
//          deterministic two-stage gate reduction (no atomics).
//
#define SB   64            // batch
#define SS   46            // seq
#define SE   1024          // embed
#define SI   2048          // inner
#define ROWS (SB*SS)       // 2944
#define NHH  4             // mLSTM heads
#define DHH  512           // head dim
#define NHQ_ 512           // headwise 4x4 heads
#define OUTD 512

typedef __attribute__((ext_vector_type(8))) short bf16x8;
typedef __attribute__((ext_vector_type(4))) float f32x4;

__device__ __forceinline__ void gload_lds16(const void* g, void* lds) {
  __builtin_amdgcn_global_load_lds(
      (const __attribute__((address_space(1))) unsigned int*)g,
      (__attribute__((address_space(3))) unsigned int*)lds, 16, 0, 0);
}

__device__ __forceinline__ float bf2f(short s) {
  union { unsigned int u; float f; } x;
  x.u = ((unsigned int)(unsigned short)s) << 16;
  return x.f;
}

// ---------------------------------------------------------------------------
// LayerNorm -> bf16 out
__global__ __launch_bounds__(256) void ln_bf16_kernel(
    const float* __restrict__ x, size_t row_stride,
    const float* __restrict__ w, __hip_bfloat16* __restrict__ out, int ncols) {
  const float* xr = x + (size_t)blockIdx.x * row_stride;
  float s1 = 0.f, s2 = 0.f;
  for (int i = threadIdx.x; i < ncols; i += 256) { float v = xr[i]; s1 += v; s2 += v*v; }
  __shared__ float r1[4], r2[4];
  for (int off = 32; off; off >>= 1) { s1 += __shfl_down(s1, off); s2 += __shfl_down(s2, off); }
  if ((threadIdx.x & 63) == 0) { r1[threadIdx.x >> 6] = s1; r2[threadIdx.x >> 6] = s2; }
  __syncthreads();
  s1 = r1[0]+r1[1]+r1[2]+r1[3];
  s2 = r2[0]+r2[1]+r2[2]+r2[3];
  const float invn = 1.f / (float)ncols;
  const float mu = s1 * invn;
  const float var = s2 * invn - mu*mu;
  const float rs = rsqrtf(var + 1e-5f);
  __hip_bfloat16* orow = out + (size_t)blockIdx.x * ncols;
  for (int i = threadIdx.x; i < ncols; i += 256)
    orow[i] = __float2bfloat16((xr[i]-mu)*rs*w[i]);
}

// LayerNorm fp32 out (post-LN before projection)
__global__ __launch_bounds__(256) void ln_kernel(
    const float* __restrict__ x, size_t row_stride,
    const float* __restrict__ w, float* __restrict__ out, int ncols) {
  const float* xr = x + (size_t)blockIdx.x * row_stride;
  float s1 = 0.f, s2 = 0.f;
  for (int i = threadIdx.x; i < ncols; i += 256) { float v = xr[i]; s1 += v; s2 += v*v; }
  __shared__ float r1[4], r2[4];
  for (int off = 32; off; off >>= 1) { s1 += __shfl_down(s1, off); s2 += __shfl_down(s2, off); }
  if ((threadIdx.x & 63) == 0) { r1[threadIdx.x >> 6] = s1; r2[threadIdx.x >> 6] = s2; }
  __syncthreads();
  s1 = r1[0]+r1[1]+r1[2]+r1[3];
  s2 = r2[0]+r2[1]+r2[2]+r2[3];
  const float invn = 1.f / (float)ncols;
  const float mu = s1 * invn;
  const float var = s2 * invn - mu*mu;
  const float rs = rsqrtf(var + 1e-5f);
  float* orow = out + (size_t)blockIdx.x * ncols;
  for (int i = threadIdx.x; i < ncols; i += 256) orow[i] = (xr[i]-mu)*rs*w[i];
}

// ---------------------------------------------------------------------------
// Transpose + convert: W [K][N] fp32 -> Wt [N][K] bf16.  32x32 tiles.
__global__ __launch_bounds__(256) void transpose_bf16_kernel(
    const float* __restrict__ W, __hip_bfloat16* __restrict__ Wt, int K, int N) {
  __shared__ float tile[32][33];
  const int k0 = blockIdx.y * 32, n0 = blockIdx.x * 32;
  const int tr = threadIdx.x >> 5;
  const int tc = threadIdx.x & 31;
#pragma unroll
  for (int i = 0; i < 4; ++i)
    tile[tr + i*8][tc] = W[(size_t)(k0 + tr + i*8)*N + n0 + tc];
  __syncthreads();
#pragma unroll
  for (int i = 0; i < 4; ++i)
    Wt[(size_t)(n0 + tr + i*8)*K + k0 + tc] = __float2bfloat16(tile[tc][tr + i*8]);
}

// ---------------------------------------------------------------------------
// bf16 MFMA GEMM: C[M,N] (+)= A[M,K] * Bt[N,K]^T.  128x128 tile, BK=32.
__global__ __launch_bounds__(256) void gemm_mfma(
    const __hip_bfloat16* __restrict__ A, int lda,
    const __hip_bfloat16* __restrict__ Bt, int ldb,
    float* __restrict__ C, int ldc, int K, int accum) {
  __shared__ short As[128*32];
  __shared__ short Bs[128*32];
  const int t = threadIdx.x;
  const int lane = t & 63;
  const int w = t >> 6;
  const int wr = w >> 1, wc = w & 1;
  const int l15 = lane & 15, lg = lane >> 4;
  const int row0 = blockIdx.y * 128, col0 = blockIdx.x * 128;
  f32x4 acc[4][4];
#pragma unroll
  for (int m = 0; m < 4; ++m)
#pragma unroll
    for (int n = 0; n < 4; ++n) acc[m][n] = (f32x4){0.f,0.f,0.f,0.f};

  for (int k0 = 0; k0 < K; k0 += 32) {
#pragma unroll
    for (int c = 0; c < 2; ++c) {
      const int L  = c*4096 + t*16;
      const int r  = L >> 6;
      const int kk = (L & 63) >> 1;
      gload_lds16(A  + (size_t)(row0 + r)*lda + k0 + kk, (char*)As + L);
      gload_lds16(Bt + (size_t)(col0 + r)*ldb + k0 + kk, (char*)Bs + L);
    }
    __syncthreads();
    bf16x8 af[4], bfr[4];
#pragma unroll
    for (int m = 0; m < 4; ++m)
      af[m] = *(const bf16x8*)&As[(wr*64 + m*16 + l15)*32 + lg*8];
#pragma unroll
    for (int n = 0; n < 4; ++n)
      bfr[n] = *(const bf16x8*)&Bs[(wc*64 + n*16 + l15)*32 + lg*8];
#pragma unroll
    for (int m = 0; m < 4; ++m)
#pragma unroll
      for (int n = 0; n < 4; ++n)
        acc[m][n] = __builtin_amdgcn_mfma_f32_16x16x32_bf16(af[m], bfr[n], acc[m][n], 0, 0, 0);
    __syncthreads();
  }
#pragma unroll
  for (int m = 0; m < 4; ++m) {
#pragma unroll
    for (int n = 0; n < 4; ++n) {
      const int cc = col0 + wc*64 + n*16 + l15;
#pragma unroll
      for (int j = 0; j < 4; ++j) {
        const int rr = row0 + wr*64 + m*16 + lg*4 + j;
        float* p = C + (size_t)rr*ldc + cc;
        if (accum) *p += acc[m][n][j]; else *p = acc[m][n][j];
      }
    }
  }
}

// ---------------------------------------------------------------------------
// Fused: causal conv(K=4)+SiLU -> xact; headwise 4x4 q/k/v -> bf16 buffers;
// gate partial dot-products -> part[row][chunk][8].
// Grid: ROWS*8 blocks; block (row, chunk of 256 channels).
__global__ __launch_bounds__(256) void conv_head_gate_kernel(
    const float* __restrict__ up, const float* __restrict__ cw,
    const float* __restrict__ cb,
    const float* __restrict__ wq, const float* __restrict__ wk,
    const float* __restrict__ wv,
    const float* __restrict__ igw, const float* __restrict__ fgw,
    float* __restrict__ xact,
    __hip_bfloat16* __restrict__ qb, __hip_bfloat16* __restrict__ kb,
    __hip_bfloat16* __restrict__ vb, float* __restrict__ part) {
  const int row   = blockIdx.x >> 3;
  const int chunk = blockIdx.x & 7;
  const int t = threadIdx.x;
  const int c = chunk*256 + t;
  const int s = row % SS;

  __shared__ float xs[256];   // conv+silu outputs (x_act)
  __shared__ float us[256];   // raw x_in values
  __shared__ float red[4][8];

  // causal depthwise conv + bias + SiLU
  float acc = cb[c];
  const float* w4 = cw + (size_t)c * 4;
#pragma unroll
  for (int j = 0; j < 4; ++j) {
    const int ss = s - 3 + j;
    if (ss >= 0) acc += up[(size_t)(row - 3 + j) * (2*SI) + c] * w4[j];
  }
  const float xa = acc / (1.f + expf(-acc));
  xact[(size_t)row * SI + c] = xa;
  xs[t] = xa;
  us[t] = up[(size_t)row * (2*SI) + c];
  __syncthreads();

  // headwise 4x4
  const int hq = c >> 2, o = c & 3;
  const int gb = t & ~3;
  const size_t wo = ((size_t)hq*4 + o)*4;
  const float* wq4 = wq + wo;
  const float* wk4 = wk + wo;
  const float* wv4 = wv + wo;
  float q = 0.f, k = 0.f, v = 0.f;
#pragma unroll
  for (int d = 0; d < 4; ++d) {
    q += xs[gb+d]*wq4[d]; k += xs[gb+d]*wk4[d]; v += us[gb+d]*wv4[d];
  }
  const int b = row / SS;
  const int h = c >> 9, dd = c & 511;
  const size_t dst = (((size_t)b*NHH + h)*SS + s)*DHH + dd;
  qb[dst] = __float2bfloat16(q);
  kb[dst] = __float2bfloat16(k);
  vb[dst] = __float2bfloat16(v);

  // gate partials: channels c (q), 2048+c (k), 4096+c (v)
  const float4 wiq = *(const float4*)(igw + (size_t)c*4);
  const float4 wik = *(const float4*)(igw + (size_t)(2048+c)*4);
  const float4 wiv = *(const float4*)(igw + (size_t)(4096+c)*4);
  const float4 wfq = *(const float4*)(fgw + (size_t)c*4);
  const float4 wfk = *(const float4*)(fgw + (size_t)(2048+c)*4);
  const float4 wfv = *(const float4*)(fgw + (size_t)(4096+c)*4);
  float a8[8];
  a8[0] = q*wiq.x + k*wik.x + v*wiv.x;
  a8[1] = q*wiq.y + k*wik.y + v*wiv.y;
  a8[2] = q*wiq.z + k*wik.z + v*wiv.z;
  a8[3] = q*wiq.w + k*wik.w + v*wiv.w;
  a8[4] = q*wfq.x + k*wfk.x + v*wfv.x;
  a8[5] = q*wfq.y + k*wfk.y + v*wfv.y;
  a8[6] = q*wfq.z + k*wfk.z + v*wfv.z;
  a8[7] = q*wfq.w + k*wfk.w + v*wfv.w;
  for (int off = 32; off; off >>= 1)
#pragma unroll
    for (int g = 0; g < 8; ++g) a8[g] += __shfl_down(a8[g], off);
  if ((t & 63) == 0)
#pragma unroll
    for (int g = 0; g < 8; ++g) red[t >> 6][g] = a8[g];
  __syncthreads();
  if (t < 8)
    part[(size_t)row*64 + chunk*8 + t] = red[0][t]+red[1][t]+red[2][t]+red[3][t];
}

// ---------------------------------------------------------------------------
// Gate reduce: ipre/fpre[b,h,s] = sum_chunk part[row][chunk][g] + bias
__global__ __launch_bounds__(256) void gate_reduce_kernel(
    const float* __restrict__ part,
    const float* __restrict__ igb, const float* __restrict__ fgb,
    float* __restrict__ ipre, float* __restrict__ fpre) {
  const int idx = blockIdx.x * 256 + threadIdx.x;
  if (idx >= ROWS * 8) return;
  const int row = idx >> 3, g = idx & 7;
  const int h = g & 3;
  const bool isF = g >= 4;
  float s = 0.f;
#pragma unroll
  for (int ch = 0; ch < 8; ++ch) s += part[(size_t)row*64 + ch*8 + g];
  s += isF ? fgb[h] : igb[h];
  const int b = row / SS, ss = row % SS;
  float* dstp = isF ? fpre : ipre;
  dstp[((size_t)b*NHH + h)*SS + ss] = s;
}

// ---------------------------------------------------------------------------
// mLSTM per (b,head), MFMA QK^T + VALU PV.  h -> hbuf [b][h][s][d] fp32.
__global__ __launch_bounds__(256) void mlstm_mfma_kernel(
    const __hip_bfloat16* __restrict__ qb, const __hip_bfloat16* __restrict__ kb,
    const __hip_bfloat16* __restrict__ vb,
    const float* __restrict__ ipre, const float* __restrict__ fpre,
    float* __restrict__ hbuf) {
  const int bh = blockIdx.x;                 // b*4 + h
  const int t = threadIdx.x;
  const int lane = t & 63, wid = t >> 6;
  const int l15 = lane & 15, lg = lane >> 4;

  __shared__ short QKs[2][48*264];           // Q/K half-D tiles [48][264], pad 264
  __shared__ float Cs[46][48];
  __shared__ float cum[46], mmv[46], ips[46], fps[46], inv[46];
  short* Vs = &QKs[0][0];                    // alias: V [46][520] bf16

  if (t < SS) { ips[t] = ipre[bh*SS + t]; fps[t] = fpre[bh*SS + t]; }

  int prs[3]; int np = 0;
  for (int p = wid; p < 9; p += 4) prs[np++] = p;
  f32x4 acc[3];
#pragma unroll
  for (int i = 0; i < 3; ++i) acc[i] = (f32x4){0.f,0.f,0.f,0.f};

  for (int ph = 0; ph < 2; ++ph) {
    __syncthreads();
    for (int i = t; i < 48*32; i += 256) {
      const int row = i >> 5, oc = i & 31;
      bf16x8 vq = {0,0,0,0,0,0,0,0}, vk = {0,0,0,0,0,0,0,0};
      if (row < SS) {
        const size_t src = ((size_t)bh*SS + row)*DHH + ph*256 + oc*8;
        vq = *(const bf16x8*)(qb + src);
        vk = *(const bf16x8*)(kb + src);
      }
      *(bf16x8*)&QKs[0][row*264 + oc*8] = vq;
      *(bf16x8*)&QKs[1][row*264 + oc*8] = vk;
    }
    __syncthreads();
#pragma unroll
    for (int kc = 0; kc < 8; ++kc) {
      for (int i = 0; i < np; ++i) {
        const int mt = prs[i] / 3, nt = prs[i] - 3*(prs[i]/3);
        const bf16x8 a = *(const bf16x8*)&QKs[0][(mt*16 + l15)*264 + kc*32 + lg*8];
        const bf16x8 b = *(const bf16x8*)&QKs[1][(nt*16 + l15)*264 + kc*32 + lg*8];
        acc[i] = __builtin_amdgcn_mfma_f32_16x16x32_bf16(a, b, acc[i], 0, 0, 0);
      }
    }
  }
  __syncthreads();
  if (t == 0) {
    float c = 0.f, rmax = -INFINITY;
    for (int s = 0; s < SS; ++s) {
      const float xv = fps[s];
      const float lf = fminf(xv, 0.f) - log1pf(expf(-fabsf(xv)));
      c += lf; cum[s] = c;
      rmax = fmaxf(rmax, ips[s] - c);
      mmv[s] = c + rmax;
    }
  }
  for (int i = t; i < SS*64; i += 256) {
    const int row = i >> 6, oc = i & 63;
    *(bf16x8*)&Vs[row*520 + oc*8] =
        *(const bf16x8*)(vb + ((size_t)bh*SS + row)*DHH + oc*8);
  }
  __syncthreads();
  const float rsq = 0.04419417382415922f;
  for (int i = 0; i < np; ++i) {
    const int mt = prs[i] / 3, nt = prs[i] - 3*(prs[i]/3);
    const int s = nt*16 + l15;
    if (s < SS) {
#pragma unroll
      for (int j = 0; j < 4; ++j) {
        const int tt = mt*16 + lg*4 + j;
        if (tt < SS) {
          float wgt = 0.f;
          if (s <= tt) wgt = rsq * expf(cum[tt] - cum[s] + ips[s] - mmv[tt]);
          Cs[tt][s] = acc[i][j] * wgt;
        }
      }
    }
  }
  __syncthreads();
  if (t < SS) {
    float ssum = 0.f;
    for (int s = 0; s <= t; ++s) ssum += Cs[t][s];
    inv[t] = 1.f / (fmaxf(fabsf(ssum), expf(-mmv[t])) + 1e-6f);
  }
  __syncthreads();
  for (int it = 0; it < 12; ++it) {
    const int tt = wid + it*4;
    if (tt >= SS) break;
    float a[8];
#pragma unroll
    for (int j = 0; j < 8; ++j) a[j] = 0.f;
    for (int s = 0; s <= tt; ++s) {
      const float c = Cs[tt][s];
      const bf16x8 v8 = *(const bf16x8*)&Vs[s*520 + lane*8];
#pragma unroll
      for (int j = 0; j < 8; ++j) a[j] += c * bf2f(v8[j]);
    }
    const float sc = inv[tt];
    float* dst = hbuf + ((size_t)bh*SS + tt)*DHH + lane*8;
    float4 o0 = {a[0]*sc, a[1]*sc, a[2]*sc, a[3]*sc};
    float4 o1 = {a[4]*sc, a[5]*sc, a[6]*sc, a[7]*sc};
    *(float4*)dst = o0;
    *(float4*)(dst + 4) = o1;
  }
}

// ---------------------------------------------------------------------------
// Per-(b,s,head) LN over DH from hbuf, * mhn_w, + skip*x_act, * silu(z) -> bf16.
__global__ __launch_bounds__(256) void mhnorm_kernel(
    const float* __restrict__ hbuf, const float* __restrict__ xact,
    const float* __restrict__ up, const float* __restrict__ skip,
    const float* __restrict__ mhn, __hip_bfloat16* __restrict__ habf) {
  const int bs = blockIdx.x >> 2;
  const int h  = blockIdx.x & 3;
  const int b = bs / SS, s = bs - b*SS;
  const float* hrow = hbuf + (((size_t)b*NHH + h)*SS + s)*DHH;
  const float v0 = hrow[threadIdx.x], v1 = hrow[threadIdx.x + 256];
  float s1 = v0 + v1, s2 = v0*v0 + v1*v1;
  __shared__ float r1[4], r2[4];
  for (int off = 32; off; off >>= 1) { s1 += __shfl_down(s1, off); s2 += __shfl_down(s2, off); }
  if ((threadIdx.x & 63) == 0) { r1[threadIdx.x >> 6] = s1; r2[threadIdx.x >> 6] = s2; }
  __syncthreads();
  s1 = r1[0]+r1[1]+r1[2]+r1[3];
  s2 = r2[0]+r2[1]+r2[2]+r2[3];
  const float mu = s1 * (1.f/512.f);
  const float var = s2 * (1.f/512.f) - mu*mu;
  const float rs = rsqrtf(var + 1e-5f);
  const float vv[2] = {v0, v1};
#pragma unroll
  for (int ii = 0; ii < 2; ++ii) {
    const int i = threadIdx.x + ii*256;
    const int c = h*DHH + i;
    const float hv = (vv[ii]-mu)*rs*mhn[c] + skip[c]*xact[(size_t)bs*SI + c];
    const float zv = up[(size_t)bs*(2*SI) + SI + c];
    habf[(size_t)bs*SI + c] = __float2bfloat16(hv * (zv / (1.f + expf(-zv))));
  }
}

// ---------------------------------------------------------------------------
// Final projection
__global__ __launch_bounds__(256) void proj_kernel(
    const float* __restrict__ lastln, const float* __restrict__ pw,
    const float* __restrict__ pb, float* __restrict__ out) {
  const int b = blockIdx.x;
  __shared__ float xs[SE];
  for (int i = threadIdx.x; i < SE; i += 256) xs[i] = lastln[(size_t)b*SE + i];
  __syncthreads();
  for (int o = threadIdx.x; o < OUTD; o += 256) {
    float acc = pb[o];
    for (int k = 0; k < SE; ++k) acc += xs[k] * pw[(size_t)k*OUTD + o];
    out[(size_t)b*OUTD + o] = acc;
  }
}

// ---------------------------------------------------------------------------
extern "C" void kernel_launch(void* const* d_in, const int* in_sizes, int n_in,
                              void* d_out, int out_size, void* d_ws, size_t ws_size,
                              hipStream_t stream) {
  const float* x_in   = (const float*)d_in[0];
  const float* ln_w   = (const float*)d_in[1];
  const float* w_up   = (const float*)d_in[2];
  const float* conv_w = (const float*)d_in[3];
  const float* conv_b = (const float*)d_in[4];
  const float* wq     = (const float*)d_in[5];
  const float* wk     = (const float*)d_in[6];
  const float* wv     = (const float*)d_in[7];
  const float* ig_w   = (const float*)d_in[8];
  const float* ig_b   = (const float*)d_in[9];
  const float* fg_w   = (const float*)d_in[10];
  const float* fg_b   = (const float*)d_in[11];
  const float* skip   = (const float*)d_in[12];
  const float* mhn_w  = (const float*)d_in[13];
  const float* w_down = (const float*)d_in[14];
  const float* post_w = (const float*)d_in[15];
  const float* proj_w = (const float*)d_in[16];
  const float* proj_b = (const float*)d_in[17];
  float* out = (float*)d_out;

  float* ws = (float*)d_ws;
  float* xbuf   = ws;                                   // ROWS*SE
  float* upbuf  = xbuf  + (size_t)ROWS*SE;              // ROWS*2*SI
  float* xact   = upbuf + (size_t)ROWS*2*SI;            // ROWS*SI
  float* hbuf   = xact  + (size_t)ROWS*SI;              // ROWS*SI ([b][h][s][d])
  float* ipre   = hbuf  + (size_t)ROWS*SI;              // B*NH*S
  float* fpre   = ipre  + (size_t)SB*NHH*SS;
  float* lastln = fpre  + (size_t)SB*NHH*SS;            // B*SE
  float* part   = lastln + (size_t)SB*SE;               // ROWS*64
  __hip_bfloat16* lnb  = (__hip_bfloat16*)(part + (size_t)ROWS*64);  // ROWS*SE
  __hip_bfloat16* qb   = lnb  + (size_t)ROWS*SE;        // ROWS*SI each, [b][h][s][d]
  __hip_bfloat16* kb   = qb   + (size_t)ROWS*SI;
  __hip_bfloat16* vb   = kb   + (size_t)ROWS*SI;
  __hip_bfloat16* habf = vb   + (size_t)ROWS*SI;        // ROWS*SI
  __hip_bfloat16* wT   = habf + (size_t)ROWS*SI;        // 4096*1024

  hipMemcpyAsync(xbuf, x_in, (size_t)ROWS*SE*sizeof(float),
                 hipMemcpyDeviceToDevice, stream);

  for (int blk = 0; blk < 8; ++blk) {
    const float* lw   = ln_w   + (size_t)blk*SE;
    const float* wu   = w_up   + (size_t)blk*SE*2*SI;
    const float* cw   = conv_w + (size_t)blk*SI*4;
    const float* cb   = conv_b + (size_t)blk*SI;
    const float* wqb  = wq     + (size_t)blk*NHQ_*16;
    const float* wkb  = wk     + (size_t)blk*NHQ_*16;
    const float* wvb  = wv     + (size_t)blk*NHQ_*16;
    const float* igwb = ig_w   + (size_t)blk*3*SI*NHH;
    const float* igbb = ig_b   + (size_t)blk*NHH;
    const float* fgwb = fg_w   + (size_t)blk*3*SI*NHH;
    const float* fgbb = fg_b   + (size_t)blk*NHH;
    const float* skb  = skip   + (size_t)blk*SI;
    const float* mhb  = mhn_w  + (size_t)blk*SI;
    const float* wdb  = w_down + (size_t)blk*SI*SE;

    transpose_bf16_kernel<<<dim3(128, 32), 256, 0, stream>>>(wu, wT, SE, 2*SI);
    ln_bf16_kernel<<<ROWS, 256, 0, stream>>>(xbuf, SE, lw, lnb, SE);
    gemm_mfma<<<dim3(32, 23), 256, 0, stream>>>(lnb, SE, wT, SE, upbuf, 2*SI, SE, 0);
    conv_head_gate_kernel<<<ROWS*8, 256, 0, stream>>>(
        upbuf, cw, cb, wqb, wkb, wvb, igwb, fgwb, xact, qb, kb, vb, part);
    gate_reduce_kernel<<<(ROWS*8+255)/256, 256, 0, stream>>>(part, igbb, fgbb, ipre, fpre);
    mlstm_mfma_kernel<<<SB*NHH, 256, 0, stream>>>(qb, kb, vb, ipre, fpre, hbuf);
    mhnorm_kernel<<<ROWS*NHH, 256, 0, stream>>>(hbuf, xact, upbuf, skb, mhb, habf);
    transpose_bf16_kernel<<<dim3(32, 64), 256, 0, stream>>>(wdb, wT, SI, SE);
    gemm_mfma<<<dim3(8, 23), 256, 0, stream>>>(habf, SI, wT, SI, xbuf, SE, SI, 1);
  }
  ln_kernel<<<SB, 256, 0, stream>>>(xbuf + (size_t)(SS-1)*SE, (size_t)SS*SE, post_w, lastln, SE);
  proj_kernel<<<SB, 256, 0, stream>>>(lastln, proj_w, proj_b, out);
}

// Round 5
// 1769.904 us; speedup vs baseline: 4.8745x; 1.1415x over previous
//
#include <hip/hip_runtime.h>
#include <hip/hip_bf16.h>
#include <math.h>

// xLSTM block stack: 8 sequential blocks, then post-LN + projection.
// Round 4: parallel proj; mhnorm+gate_reduce fused into mlstm; bf16 upbuf;
//          split-K down-GEMM; weight transposes hoisted out of the loop.
//
#define SB   64            // batch
#define SS   46            // seq
#define SE   1024          // embed
#define SI   2048          // inner
#define ROWS (SB*SS)       // 2944
#define NHH  4             // mLSTM heads
#define DHH  512           // head dim
#define NHQ_ 512           // headwise 4x4 heads
#define OUTD 512

typedef __attribute__((ext_vector_type(8))) short bf16x8;
typedef __attribute__((ext_vector_type(4))) float f32x4;

__device__ __forceinline__ void gload_lds16(const void* g, void* lds) {
  __builtin_amdgcn_global_load_lds(
      (const __attribute__((address_space(1))) unsigned int*)g,
      (__attribute__((address_space(3))) unsigned int*)lds, 16, 0, 0);
}

__device__ __forceinline__ float bf2f(short s) {
  union { unsigned int u; float f; } x;
  x.u = ((unsigned int)(unsigned short)s) << 16;
  return x.f;
}

// ---------------------------------------------------------------------------
// LayerNorm -> bf16 out
__global__ __launch_bounds__(256) void ln_bf16_kernel(
    const float* __restrict__ x, size_t row_stride,
    const float* __restrict__ w, __hip_bfloat16* __restrict__ out, int ncols) {
  const float* xr = x + (size_t)blockIdx.x * row_stride;
  float s1 = 0.f, s2 = 0.f;
  for (int i = threadIdx.x; i < ncols; i += 256) { float v = xr[i]; s1 += v; s2 += v*v; }
  __shared__ float r1[4], r2[4];
  for (int off = 32; off; off >>= 1) { s1 += __shfl_down(s1, off); s2 += __shfl_down(s2, off); }
  if ((threadIdx.x & 63) == 0) { r1[threadIdx.x >> 6] = s1; r2[threadIdx.x >> 6] = s2; }
  __syncthreads();
  s1 = r1[0]+r1[1]+r1[2]+r1[3];
  s2 = r2[0]+r2[1]+r2[2]+r2[3];
  const float invn = 1.f / (float)ncols;
  const float mu = s1 * invn;
  const float var = s2 * invn - mu*mu;
  const float rs = rsqrtf(var + 1e-5f);
  __hip_bfloat16* orow = out + (size_t)blockIdx.x * ncols;
  for (int i = threadIdx.x; i < ncols; i += 256)
    orow[i] = __float2bfloat16((xr[i]-mu)*rs*w[i]);
}

// LayerNorm fp32 out (post-LN before projection)
__global__ __launch_bounds__(256) void ln_kernel(
    const float* __restrict__ x, size_t row_stride,
    const float* __restrict__ w, float* __restrict__ out, int ncols) {
  const float* xr = x + (size_t)blockIdx.x * row_stride;
  float s1 = 0.f, s2 = 0.f;
  for (int i = threadIdx.x; i < ncols; i += 256) { float v = xr[i]; s1 += v; s2 += v*v; }
  __shared__ float r1[4], r2[4];
  for (int off = 32; off; off >>= 1) { s1 += __shfl_down(s1, off); s2 += __shfl_down(s2, off); }
  if ((threadIdx.x & 63) == 0) { r1[threadIdx.x >> 6] = s1; r2[threadIdx.x >> 6] = s2; }
  __syncthreads();
  s1 = r1[0]+r1[1]+r1[2]+r1[3];
  s2 = r2[0]+r2[1]+r2[2]+r2[3];
  const float invn = 1.f / (float)ncols;
  const float mu = s1 * invn;
  const float var = s2 * invn - mu*mu;
  const float rs = rsqrtf(var + 1e-5f);
  float* orow = out + (size_t)blockIdx.x * ncols;
  for (int i = threadIdx.x; i < ncols; i += 256) orow[i] = (xr[i]-mu)*rs*w[i];
}

// ---------------------------------------------------------------------------
// Transpose + convert (all 8 layers): W [z][K][N] fp32 -> Wt [z][N][K] bf16.
__global__ __launch_bounds__(256) void transpose_bf16_kernel(
    const float* __restrict__ W, __hip_bfloat16* __restrict__ Wt, int K, int N) {
  __shared__ float tile[32][33];
  const int z = blockIdx.z;
  const float* Wz = W + (size_t)z*K*N;
  __hip_bfloat16* Wtz = Wt + (size_t)z*K*N;
  const int k0 = blockIdx.y * 32, n0 = blockIdx.x * 32;
  const int tr = threadIdx.x >> 5;
  const int tc = threadIdx.x & 31;
#pragma unroll
  for (int i = 0; i < 4; ++i)
    tile[tr + i*8][tc] = Wz[(size_t)(k0 + tr + i*8)*N + n0 + tc];
  __syncthreads();
#pragma unroll
  for (int i = 0; i < 4; ++i)
    Wtz[(size_t)(n0 + tr + i*8)*K + k0 + tc] = __float2bfloat16(tile[tc][tr + i*8]);
}

// ---------------------------------------------------------------------------
// bf16 MFMA GEMM: C[M,N] = A[M,K_z] * Bt[N,K_z]^T over this z's K-slice.
// mode 0: fp32 store; mode 1: fp32 accumulate; mode 2: bf16 store.
// gridDim.z slices K; C += z*cstride (fp32/bf16 elems per mode).
__global__ __launch_bounds__(256) void gemm_mfma(
    const __hip_bfloat16* __restrict__ A, int lda,
    const __hip_bfloat16* __restrict__ Bt, int ldb,
    void* __restrict__ Cv, int ldc, int K, size_t cstride, int mode) {
  __shared__ short As[128*32];
  __shared__ short Bs[128*32];
  const int t = threadIdx.x;
  const int lane = t & 63;
  const int w = t >> 6;
  const int wr = w >> 1, wc = w & 1;
  const int l15 = lane & 15, lg = lane >> 4;
  const int row0 = blockIdx.y * 128, col0 = blockIdx.x * 128;
  const int Kper = K / gridDim.z;
  const int kbeg = blockIdx.z * Kper, kend = kbeg + Kper;
  f32x4 acc[4][4];
#pragma unroll
  for (int m = 0; m < 4; ++m)
#pragma unroll
    for (int n = 0; n < 4; ++n) acc[m][n] = (f32x4){0.f,0.f,0.f,0.f};

  for (int k0 = kbeg; k0 < kend; k0 += 32) {
#pragma unroll
    for (int c = 0; c < 2; ++c) {
      const int L  = c*4096 + t*16;
      const int r  = L >> 6;
      const int kk = (L & 63) >> 1;
      gload_lds16(A  + (size_t)(row0 + r)*lda + k0 + kk, (char*)As + L);
      gload_lds16(Bt + (size_t)(col0 + r)*ldb + k0 + kk, (char*)Bs + L);
    }
    __syncthreads();
    bf16x8 af[4], bfr[4];
#pragma unroll
    for (int m = 0; m < 4; ++m)
      af[m] = *(const bf16x8*)&As[(wr*64 + m*16 + l15)*32 + lg*8];
#pragma unroll
    for (int n = 0; n < 4; ++n)
      bfr[n] = *(const bf16x8*)&Bs[(wc*64 + n*16 + l15)*32 + lg*8];
#pragma unroll
    for (int m = 0; m < 4; ++m)
#pragma unroll
      for (int n = 0; n < 4; ++n)
        acc[m][n] = __builtin_amdgcn_mfma_f32_16x16x32_bf16(af[m], bfr[n], acc[m][n], 0, 0, 0);
    __syncthreads();
  }
#pragma unroll
  for (int m = 0; m < 4; ++m) {
#pragma unroll
    for (int n = 0; n < 4; ++n) {
      const int cc = col0 + wc*64 + n*16 + l15;
#pragma unroll
      for (int j = 0; j < 4; ++j) {
        const int rr = row0 + wr*64 + m*16 + lg*4 + j;
        if (mode == 2) {
          __hip_bfloat16* p = (__hip_bfloat16*)Cv + (size_t)rr*ldc + cc;
          *p = __float2bfloat16(acc[m][n][j]);
        } else {
          float* p = (float*)Cv + blockIdx.z*cstride + (size_t)rr*ldc + cc;
          if (mode == 1) *p += acc[m][n][j]; else *p = acc[m][n][j];
        }
      }
    }
  }
}

// ---------------------------------------------------------------------------
// Split-K reduce: xbuf += p0 + p1   (float4 over ROWS*SE)
__global__ __launch_bounds__(256) void downred_kernel(
    float* __restrict__ xbuf, const float* __restrict__ part) {
  const size_t i = ((size_t)blockIdx.x * 256 + threadIdx.x) * 4;
  if (i >= (size_t)ROWS*SE) return;
  float4 x = *(float4*)(xbuf + i);
  const float4 p0 = *(const float4*)(part + i);
  const float4 p1 = *(const float4*)(part + (size_t)ROWS*SE + i);
  x.x += p0.x + p1.x; x.y += p0.y + p1.y;
  x.z += p0.z + p1.z; x.w += p0.w + p1.w;
  *(float4*)(xbuf + i) = x;
}

// ---------------------------------------------------------------------------
// Fused: causal conv(K=4)+SiLU -> xact; headwise 4x4 q/k/v -> bf16 buffers;
// gate partial dot-products -> part[row][chunk][8].  up is bf16 now.
__global__ __launch_bounds__(256) void conv_head_gate_kernel(
    const __hip_bfloat16* __restrict__ up, const float* __restrict__ cw,
    const float* __restrict__ cb,
    const float* __restrict__ wq, const float* __restrict__ wk,
    const float* __restrict__ wv,
    const float* __restrict__ igw, const float* __restrict__ fgw,
    float* __restrict__ xact,
    __hip_bfloat16* __restrict__ qb, __hip_bfloat16* __restrict__ kb,
    __hip_bfloat16* __restrict__ vb, float* __restrict__ part) {
  const int row   = blockIdx.x >> 3;
  const int chunk = blockIdx.x & 7;
  const int t = threadIdx.x;
  const int c = chunk*256 + t;
  const int s = row % SS;

  __shared__ float xs[256];   // conv+silu outputs (x_act)
  __shared__ float us[256];   // raw x_in values
  __shared__ float red[4][8];

  const float4 w4 = *(const float4*)(cw + (size_t)c * 4);
  const float wtap[4] = {w4.x, w4.y, w4.z, w4.w};
  float acc = cb[c];
#pragma unroll
  for (int j = 0; j < 4; ++j) {
    const int ss = s - 3 + j;
    if (ss >= 0) acc += bf2f(((const short*)up)[(size_t)(row - 3 + j) * (2*SI) + c]) * wtap[j];
  }
  const float xa = acc / (1.f + expf(-acc));
  xact[(size_t)row * SI + c] = xa;
  xs[t] = xa;
  us[t] = bf2f(((const short*)up)[(size_t)row * (2*SI) + c]);
  __syncthreads();

  // headwise 4x4
  const int hq = c >> 2, o = c & 3;
  const int gb = t & ~3;
  const size_t wo = ((size_t)hq*4 + o)*4;
  const float* wq4 = wq + wo;
  const float* wk4 = wk + wo;
  const float* wv4 = wv + wo;
  float q = 0.f, k = 0.f, v = 0.f;
#pragma unroll
  for (int d = 0; d < 4; ++d) {
    q += xs[gb+d]*wq4[d]; k += xs[gb+d]*wk4[d]; v += us[gb+d]*wv4[d];
  }
  const int b = row / SS;
  const int h = c >> 9, dd = c & 511;
  const size_t dst = (((size_t)b*NHH + h)*SS + s)*DHH + dd;
  qb[dst] = __float2bfloat16(q);
  kb[dst] = __float2bfloat16(k);
  vb[dst] = __float2bfloat16(v);

  // gate partials
  const float4 wiq = *(const float4*)(igw + (size_t)c*4);
  const float4 wik = *(const float4*)(igw + (size_t)(2048+c)*4);
  const float4 wiv = *(const float4*)(igw + (size_t)(4096+c)*4);
  const float4 wfq = *(const float4*)(fgw + (size_t)c*4);
  const float4 wfk = *(const float4*)(fgw + (size_t)(2048+c)*4);
  const float4 wfv = *(const float4*)(fgw + (size_t)(4096+c)*4);
  float a8[8];
  a8[0] = q*wiq.x + k*wik.x + v*wiv.x;
  a8[1] = q*wiq.y + k*wik.y + v*wiv.y;
  a8[2] = q*wiq.z + k*wik.z + v*wiv.z;
  a8[3] = q*wiq.w + k*wik.w + v*wiv.w;
  a8[4] = q*wfq.x + k*wfk.x + v*wfv.x;
  a8[5] = q*wfq.y + k*wfk.y + v*wfv.y;
  a8[6] = q*wfq.z + k*wfk.z + v*wfv.z;
  a8[7] = q*wfq.w + k*wfk.w + v*wfv.w;
  for (int off = 32; off; off >>= 1)
#pragma unroll
    for (int g = 0; g < 8; ++g) a8[g] += __shfl_down(a8[g], off);
  if ((t & 63) == 0)
#pragma unroll
    for (int g = 0; g < 8; ++g) red[t >> 6][g] = a8[g];
  __syncthreads();
  if (t < 8)
    part[(size_t)row*64 + chunk*8 + t] = red[0][t]+red[1][t]+red[2][t]+red[3][t];
}

// ---------------------------------------------------------------------------
// mLSTM per (b,head): gate reduce + MFMA QK^T + VALU PV + fused multi-head
// norm/skip/gate epilogue -> habf bf16 [b*s][2048].
__global__ __launch_bounds__(256) void mlstm_mfma_kernel(
    const __hip_bfloat16* __restrict__ qb, const __hip_bfloat16* __restrict__ kb,
    const __hip_bfloat16* __restrict__ vb,
    const float* __restrict__ part,
    const float* __restrict__ igb, const float* __restrict__ fgb,
    const float* __restrict__ xact, const __hip_bfloat16* __restrict__ up,
    const float* __restrict__ skip, const float* __restrict__ mhn,
    __hip_bfloat16* __restrict__ habf) {
  const int bh = blockIdx.x;                 // b*4 + h
  const int b = bh >> 2, h = bh & 3;
  const int t = threadIdx.x;
  const int lane = t & 63, wid = t >> 6;
  const int l15 = lane & 15, lg = lane >> 4;

  __shared__ short QKs[2][48*264];
  __shared__ float Cs[46][48];
  __shared__ float cum[46], mmv[46], ips[46], fps[46], inv[46];
  short* Vs = &QKs[0][0];                    // alias: V [46][520] bf16

  // gate reduce for this (b,h): ipre/fpre from partials + bias
  if (t < SS) {
    const float* pr = part + (size_t)(b*SS + t)*64;
    float si = igb[h], sf = fgb[h];
#pragma unroll
    for (int ch = 0; ch < 8; ++ch) { si += pr[ch*8 + h]; sf += pr[ch*8 + 4 + h]; }
    ips[t] = si; fps[t] = sf;
  }

  int prs[3]; int np = 0;
  for (int p = wid; p < 9; p += 4) prs[np++] = p;
  f32x4 acc[3];
#pragma unroll
  for (int i = 0; i < 3; ++i) acc[i] = (f32x4){0.f,0.f,0.f,0.f};

  for (int ph = 0; ph < 2; ++ph) {
    __syncthreads();
    for (int i = t; i < 48*32; i += 256) {
      const int row = i >> 5, oc = i & 31;
      bf16x8 vq = {0,0,0,0,0,0,0,0}, vk = {0,0,0,0,0,0,0,0};
      if (row < SS) {
        const size_t src = ((size_t)bh*SS + row)*DHH + ph*256 + oc*8;
        vq = *(const bf16x8*)(qb + src);
        vk = *(const bf16x8*)(kb + src);
      }
      *(bf16x8*)&QKs[0][row*264 + oc*8] = vq;
      *(bf16x8*)&QKs[1][row*264 + oc*8] = vk;
    }
    __syncthreads();
#pragma unroll
    for (int kc = 0; kc < 8; ++kc) {
      for (int i = 0; i < np; ++i) {
        const int mt = prs[i] / 3, nt = prs[i] - 3*(prs[i]/3);
        const bf16x8 a = *(const bf16x8*)&QKs[0][(mt*16 + l15)*264 + kc*32 + lg*8];
        const bf16x8 bb = *(const bf16x8*)&QKs[1][(nt*16 + l15)*264 + kc*32 + lg*8];
        acc[i] = __builtin_amdgcn_mfma_f32_16x16x32_bf16(a, bb, acc[i], 0, 0, 0);
      }
    }
  }
  __syncthreads();
  if (t == 0) {
    float c = 0.f, rmax = -INFINITY;
    for (int s = 0; s < SS; ++s) {
      const float xv = fps[s];
      const float lf = fminf(xv, 0.f) - log1pf(expf(-fabsf(xv)));
      c += lf; cum[s] = c;
      rmax = fmaxf(rmax, ips[s] - c);
      mmv[s] = c + rmax;
    }
  }
  for (int i = t; i < SS*64; i += 256) {
    const int row = i >> 6, oc = i & 63;
    *(bf16x8*)&Vs[row*520 + oc*8] =
        *(const bf16x8*)(vb + ((size_t)bh*SS + row)*DHH + oc*8);
  }
  __syncthreads();
  const float rsq = 0.04419417382415922f;
  for (int i = 0; i < np; ++i) {
    const int mt = prs[i] / 3, nt = prs[i] - 3*(prs[i]/3);
    const int s = nt*16 + l15;
    if (s < SS) {
#pragma unroll
      for (int j = 0; j < 4; ++j) {
        const int tt = mt*16 + lg*4 + j;
        if (tt < SS) {
          float wgt = 0.f;
          if (s <= tt) wgt = rsq * expf(cum[tt] - cum[s] + ips[s] - mmv[tt]);
          Cs[tt][s] = acc[i][j] * wgt;
        }
      }
    }
  }
  __syncthreads();
  if (t < SS) {
    float ssum = 0.f;
    for (int s = 0; s <= t; ++s) ssum += Cs[t][s];
    inv[t] = 1.f / (fmaxf(fabsf(ssum), expf(-mmv[t])) + 1e-6f);
  }
  __syncthreads();
  // PV + fused mhnorm/skip/gate epilogue
  const int c0 = h*DHH + lane*8;
  for (int it = 0; it < 12; ++it) {
    const int tt = wid + it*4;
    if (tt >= SS) break;
    float a[8];
#pragma unroll
    for (int j = 0; j < 8; ++j) a[j] = 0.f;
    for (int s = 0; s <= tt; ++s) {
      const float c = Cs[tt][s];
      const bf16x8 v8 = *(const bf16x8*)&Vs[s*520 + lane*8];
#pragma unroll
      for (int j = 0; j < 8; ++j) a[j] += c * bf2f(v8[j]);
    }
    const float sc = inv[tt];
    float s1 = 0.f, s2 = 0.f;
#pragma unroll
    for (int j = 0; j < 8; ++j) { a[j] *= sc; s1 += a[j]; s2 += a[j]*a[j]; }
#pragma unroll
    for (int off = 1; off < 64; off <<= 1) {
      s1 += __shfl_xor(s1, off); s2 += __shfl_xor(s2, off);
    }
    const float mu = s1 * (1.f/512.f);
    const float var = s2 * (1.f/512.f) - mu*mu;
    const float rs = rsqrtf(var + 1e-5f);
    const int row = b*SS + tt;
    const float4 xa0 = *(const float4*)(xact + (size_t)row*SI + c0);
    const float4 xa1 = *(const float4*)(xact + (size_t)row*SI + c0 + 4);
    const bf16x8 z8 = *(const bf16x8*)((const short*)up + (size_t)row*(2*SI) + SI + c0);
    const float4 mh0 = *(const float4*)(mhn + c0);
    const float4 mh1 = *(const float4*)(mhn + c0 + 4);
    const float4 sk0 = *(const float4*)(skip + c0);
    const float4 sk1 = *(const float4*)(skip + c0 + 4);
    const float xav[8] = {xa0.x,xa0.y,xa0.z,xa0.w,xa1.x,xa1.y,xa1.z,xa1.w};
    const float mhv[8] = {mh0.x,mh0.y,mh0.z,mh0.w,mh1.x,mh1.y,mh1.z,mh1.w};
    const float skv[8] = {sk0.x,sk0.y,sk0.z,sk0.w,sk1.x,sk1.y,sk1.z,sk1.w};
    bf16x8 o8;
#pragma unroll
    for (int j = 0; j < 8; ++j) {
      const float hv = (a[j]-mu)*rs*mhv[j] + skv[j]*xav[j];
      const float zv = bf2f(z8[j]);
      const float r = hv * (zv / (1.f + expf(-zv)));
      union { float f; unsigned int u; } cv; cv.f = r;
      // round-to-nearest-even bf16
      unsigned int lsb = (cv.u >> 16) & 1;
      cv.u += 0x7fff + lsb;
      o8[j] = (short)(cv.u >> 16);
    }
    *(bf16x8*)((short*)habf + (size_t)row*SI + c0) = o8;
  }
}

// ---------------------------------------------------------------------------
// Final projection: grid 512 = (b, o-chunk of 64); 4 waves split K.
__global__ __launch_bounds__(256) void proj2_kernel(
    const float* __restrict__ lastln, const float* __restrict__ pw,
    const float* __restrict__ pb, float* __restrict__ out) {
  const int b = blockIdx.x >> 3;
  const int och = blockIdx.x & 7;
  const int t = threadIdx.x;
  const int w = t >> 6, lane = t & 63;
  __shared__ float xs[SE];
  __shared__ float red[4][64];
  for (int i = t; i < SE; i += 256) xs[i] = lastln[(size_t)b*SE + i];
  __syncthreads();
  const int o = och*64 + lane;
  float acc = 0.f;
  const int kbeg = w*256;
#pragma unroll 8
  for (int k = kbeg; k < kbeg + 256; ++k)
    acc += xs[k] * pw[(size_t)k*OUTD + o];
  red[w][lane] = acc;
  __syncthreads();
  if (t < 64)
    out[(size_t)b*OUTD + och*64 + t] =
        red[0][t] + red[1][t] + red[2][t] + red[3][t] + pb[och*64 + t];
}

// ---------------------------------------------------------------------------
extern "C" void kernel_launch(void* const* d_in, const int* in_sizes, int n_in,
                              void* d_out, int out_size, void* d_ws, size_t ws_size,
                              hipStream_t stream) {
  const float* x_in   = (const float*)d_in[0];
  const float* ln_w   = (const float*)d_in[1];
  const float* w_up   = (const float*)d_in[2];
  const float* conv_w = (const float*)d_in[3];
  const float* conv_b = (const float*)d_in[4];
  const float* wq     = (const float*)d_in[5];
  const float* wk     = (const float*)d_in[6];
  const float* wv     = (const float*)d_in[7];
  const float* ig_w   = (const float*)d_in[8];
  const float* ig_b   = (const float*)d_in[9];
  const float* fg_w   = (const float*)d_in[10];
  const float* fg_b   = (const float*)d_in[11];
  const float* skip   = (const float*)d_in[12];
  const float* mhn_w  = (const float*)d_in[13];
  const float* w_down = (const float*)d_in[14];
  const float* post_w = (const float*)d_in[15];
  const float* proj_w = (const float*)d_in[16];
  const float* proj_b = (const float*)d_in[17];
  float* out = (float*)d_out;

  float* ws = (float*)d_ws;
  float* xbuf   = ws;                                   // ROWS*SE
  float* xact   = xbuf  + (size_t)ROWS*SE;              // ROWS*SI
  float* part   = xact  + (size_t)ROWS*SI;              // ROWS*64
  float* lastln = part  + (size_t)ROWS*64;              // SB*SE
  float* cpart  = lastln + (size_t)SB*SE;               // 2 * ROWS*SE (split-K)
  __hip_bfloat16* lnb   = (__hip_bfloat16*)(cpart + (size_t)2*ROWS*SE); // ROWS*SE
  __hip_bfloat16* upbuf = lnb   + (size_t)ROWS*SE;      // ROWS*2*SI bf16
  __hip_bfloat16* qb    = upbuf + (size_t)ROWS*2*SI;    // ROWS*SI [b][h][s][d]
  __hip_bfloat16* kb    = qb    + (size_t)ROWS*SI;
  __hip_bfloat16* vb    = kb    + (size_t)ROWS*SI;
  __hip_bfloat16* habf  = vb    + (size_t)ROWS*SI;      // ROWS*SI
  __hip_bfloat16* wTup  = habf  + (size_t)ROWS*SI;      // 8 * 4096*1024
  __hip_bfloat16* wTdn  = wTup  + (size_t)8*SE*2*SI;    // 8 * 1024*2048

  hipMemcpyAsync(xbuf, x_in, (size_t)ROWS*SE*sizeof(float),
                 hipMemcpyDeviceToDevice, stream);

  // hoisted weight transposes (all 8 layers)
  transpose_bf16_kernel<<<dim3(128, 32, 8), 256, 0, stream>>>(w_up, wTup, SE, 2*SI);
  transpose_bf16_kernel<<<dim3(32, 64, 8), 256, 0, stream>>>(w_down, wTdn, SI, SE);

  for (int blk = 0; blk < 8; ++blk) {
    const float* lw   = ln_w   + (size_t)blk*SE;
    const float* cw   = conv_w + (size_t)blk*SI*4;
    const float* cb   = conv_b + (size_t)blk*SI;
    const float* wqb  = wq     + (size_t)blk*NHQ_*16;
    const float* wkb  = wk     + (size_t)blk*NHQ_*16;
    const float* wvb  = wv     + (size_t)blk*NHQ_*16;
    const float* igwb = ig_w   + (size_t)blk*3*SI*NHH;
    const float* igbb = ig_b   + (size_t)blk*NHH;
    const float* fgwb = fg_w   + (size_t)blk*3*SI*NHH;
    const float* fgbb = fg_b   + (size_t)blk*NHH;
    const float* skb  = skip   + (size_t)blk*SI;
    const float* mhb  = mhn_w  + (size_t)blk*SI;

    ln_bf16_kernel<<<ROWS, 256, 0, stream>>>(xbuf, SE, lw, lnb, SE);
    gemm_mfma<<<dim3(32, 23, 1), 256, 0, stream>>>(
        lnb, SE, wTup + (size_t)blk*SE*2*SI, SE, upbuf, 2*SI, SE, 0, 2);
    conv_head_gate_kernel<<<ROWS*8, 256, 0, stream>>>(
        upbuf, cw, cb, wqb, wkb, wvb, igwb, fgwb, xact, qb, kb, vb, part);
    mlstm_mfma_kernel<<<SB*NHH, 256, 0, stream>>>(
        qb, kb, vb, part, igbb, fgbb, xact, upbuf, skb, mhb, habf);
    gemm_mfma<<<dim3(8, 23, 2), 256, 0, stream>>>(
        habf, SI, wTdn + (size_t)blk*SI*SE, SI, cpart, SE, SI, (size_t)ROWS*SE, 0);
    downred_kernel<<<(ROWS*SE/4 + 255)/256, 256, 0, stream>>>(xbuf, cpart);
  }
  ln_kernel<<<SB, 256, 0, stream>>>(xbuf + (size_t)(SS-1)*SE, (size_t)SS*SE, post_w, lastln, SE);
  proj2_kernel<<<SB*8, 256, 0, stream>>>(lastln, proj_w, proj_b, out);
}

// Round 6
// 1743.455 us; speedup vs baseline: 4.9485x; 1.0152x over previous
//
#include <hip/hip_runtime.h>
#include <hip/hip_bf16.h>
#include <math.h>

// xLSTM block stack: 8 sequential blocks, then post-LN + projection.
// Round 5: lnres fuses split-K reduce + residual + LN; split-K=4 down-GEMM;
//          conv_head_gate 4 rows/block (weight amortization, shuffles);
//          xact -> bf16.
//
#define SB   64            // batch
#define SS   46            // seq
#define SE   1024          // embed
#define SI   2048          // inner
#define ROWS (SB*SS)       // 2944
#define NHH  4             // mLSTM heads
#define DHH  512           // head dim
#define NHQ_ 512           // headwise 4x4 heads
#define OUTD 512
#define KSPLIT 4

typedef __attribute__((ext_vector_type(8))) short bf16x8;
typedef __attribute__((ext_vector_type(4))) float f32x4;

__device__ __forceinline__ void gload_lds16(const void* g, void* lds) {
  __builtin_amdgcn_global_load_lds(
      (const __attribute__((address_space(1))) unsigned int*)g,
      (__attribute__((address_space(3))) unsigned int*)lds, 16, 0, 0);
}

__device__ __forceinline__ float bf2f(short s) {
  union { unsigned int u; float f; } x;
  x.u = ((unsigned int)(unsigned short)s) << 16;
  return x.f;
}

// ---------------------------------------------------------------------------
// Residual-add (npart split-K partials) + LayerNorm -> bf16 out; xbuf updated.
__global__ __launch_bounds__(256) void lnres_bf16_kernel(
    float* __restrict__ xbuf, const float* __restrict__ parts, int npart,
    const float* __restrict__ w, __hip_bfloat16* __restrict__ out) {
  const int row = blockIdx.x;
  const int t = threadIdx.x;
  float vals[4];
  float s1 = 0.f, s2 = 0.f;
#pragma unroll
  for (int ii = 0; ii < 4; ++ii) {
    const int i = t + ii*256;
    float v = xbuf[(size_t)row*SE + i];
    for (int p = 0; p < npart; ++p)
      v += parts[(size_t)p*ROWS*SE + (size_t)row*SE + i];
    vals[ii] = v;
    s1 += v; s2 += v*v;
  }
  if (npart)
#pragma unroll
    for (int ii = 0; ii < 4; ++ii) xbuf[(size_t)row*SE + t + ii*256] = vals[ii];
  __shared__ float r1[4], r2[4];
  for (int off = 32; off; off >>= 1) { s1 += __shfl_down(s1, off); s2 += __shfl_down(s2, off); }
  if ((t & 63) == 0) { r1[t >> 6] = s1; r2[t >> 6] = s2; }
  __syncthreads();
  s1 = r1[0]+r1[1]+r1[2]+r1[3];
  s2 = r2[0]+r2[1]+r2[2]+r2[3];
  const float mu = s1 * (1.f/SE);
  const float var = s2 * (1.f/SE) - mu*mu;
  const float rs = rsqrtf(var + 1e-5f);
#pragma unroll
  for (int ii = 0; ii < 4; ++ii) {
    const int i = t + ii*256;
    out[(size_t)row*SE + i] = __float2bfloat16((vals[ii]-mu)*rs*w[i]);
  }
}

// Residual-add + LayerNorm fp32 out for last tokens only (post-LN).
__global__ __launch_bounds__(256) void ln_last_kernel(
    const float* __restrict__ xbuf, const float* __restrict__ parts, int npart,
    const float* __restrict__ w, float* __restrict__ out) {
  const int b = blockIdx.x;
  const int row = b*SS + SS - 1;
  const int t = threadIdx.x;
  float vals[4];
  float s1 = 0.f, s2 = 0.f;
#pragma unroll
  for (int ii = 0; ii < 4; ++ii) {
    const int i = t + ii*256;
    float v = xbuf[(size_t)row*SE + i];
    for (int p = 0; p < npart; ++p)
      v += parts[(size_t)p*ROWS*SE + (size_t)row*SE + i];
    vals[ii] = v;
    s1 += v; s2 += v*v;
  }
  __shared__ float r1[4], r2[4];
  for (int off = 32; off; off >>= 1) { s1 += __shfl_down(s1, off); s2 += __shfl_down(s2, off); }
  if ((t & 63) == 0) { r1[t >> 6] = s1; r2[t >> 6] = s2; }
  __syncthreads();
  s1 = r1[0]+r1[1]+r1[2]+r1[3];
  s2 = r2[0]+r2[1]+r2[2]+r2[3];
  const float mu = s1 * (1.f/SE);
  const float var = s2 * (1.f/SE) - mu*mu;
  const float rs = rsqrtf(var + 1e-5f);
#pragma unroll
  for (int ii = 0; ii < 4; ++ii) {
    const int i = t + ii*256;
    out[(size_t)b*SE + i] = (vals[ii]-mu)*rs*w[i];
  }
}

// ---------------------------------------------------------------------------
// Transpose + convert (all 8 layers): W [z][K][N] fp32 -> Wt [z][N][K] bf16.
__global__ __launch_bounds__(256) void transpose_bf16_kernel(
    const float* __restrict__ W, __hip_bfloat16* __restrict__ Wt, int K, int N) {
  __shared__ float tile[32][33];
  const int z = blockIdx.z;
  const float* Wz = W + (size_t)z*K*N;
  __hip_bfloat16* Wtz = Wt + (size_t)z*K*N;
  const int k0 = blockIdx.y * 32, n0 = blockIdx.x * 32;
  const int tr = threadIdx.x >> 5;
  const int tc = threadIdx.x & 31;
#pragma unroll
  for (int i = 0; i < 4; ++i)
    tile[tr + i*8][tc] = Wz[(size_t)(k0 + tr + i*8)*N + n0 + tc];
  __syncthreads();
#pragma unroll
  for (int i = 0; i < 4; ++i)
    Wtz[(size_t)(n0 + tr + i*8)*K + k0 + tc] = __float2bfloat16(tile[tc][tr + i*8]);
}

// ---------------------------------------------------------------------------
// bf16 MFMA GEMM: C[M,N] = A[M,K_z] * Bt[N,K_z]^T over this z's K-slice.
// mode 0: fp32 store (to Cv + z*cstride); mode 2: bf16 store.
__global__ __launch_bounds__(256) void gemm_mfma(
    const __hip_bfloat16* __restrict__ A, int lda,
    const __hip_bfloat16* __restrict__ Bt, int ldb,
    void* __restrict__ Cv, int ldc, int K, size_t cstride, int mode) {
  __shared__ short As[128*32];
  __shared__ short Bs[128*32];
  const int t = threadIdx.x;
  const int lane = t & 63;
  const int w = t >> 6;
  const int wr = w >> 1, wc = w & 1;
  const int l15 = lane & 15, lg = lane >> 4;
  const int row0 = blockIdx.y * 128, col0 = blockIdx.x * 128;
  const int Kper = K / gridDim.z;
  const int kbeg = blockIdx.z * Kper, kend = kbeg + Kper;
  f32x4 acc[4][4];
#pragma unroll
  for (int m = 0; m < 4; ++m)
#pragma unroll
    for (int n = 0; n < 4; ++n) acc[m][n] = (f32x4){0.f,0.f,0.f,0.f};

  for (int k0 = kbeg; k0 < kend; k0 += 32) {
#pragma unroll
    for (int c = 0; c < 2; ++c) {
      const int L  = c*4096 + t*16;
      const int r  = L >> 6;
      const int kk = (L & 63) >> 1;
      gload_lds16(A  + (size_t)(row0 + r)*lda + k0 + kk, (char*)As + L);
      gload_lds16(Bt + (size_t)(col0 + r)*ldb + k0 + kk, (char*)Bs + L);
    }
    __syncthreads();
    bf16x8 af[4], bfr[4];
#pragma unroll
    for (int m = 0; m < 4; ++m)
      af[m] = *(const bf16x8*)&As[(wr*64 + m*16 + l15)*32 + lg*8];
#pragma unroll
    for (int n = 0; n < 4; ++n)
      bfr[n] = *(const bf16x8*)&Bs[(wc*64 + n*16 + l15)*32 + lg*8];
#pragma unroll
    for (int m = 0; m < 4; ++m)
#pragma unroll
      for (int n = 0; n < 4; ++n)
        acc[m][n] = __builtin_amdgcn_mfma_f32_16x16x32_bf16(af[m], bfr[n], acc[m][n], 0, 0, 0);
    __syncthreads();
  }
#pragma unroll
  for (int m = 0; m < 4; ++m) {
#pragma unroll
    for (int n = 0; n < 4; ++n) {
      const int cc = col0 + wc*64 + n*16 + l15;
#pragma unroll
      for (int j = 0; j < 4; ++j) {
        const int rr = row0 + wr*64 + m*16 + lg*4 + j;
        if (mode == 2) {
          __hip_bfloat16* p = (__hip_bfloat16*)Cv + (size_t)rr*ldc + cc;
          *p = __float2bfloat16(acc[m][n][j]);
        } else {
          float* p = (float*)Cv + blockIdx.z*cstride + (size_t)rr*ldc + cc;
          *p = acc[m][n][j];
        }
      }
    }
  }
}

// ---------------------------------------------------------------------------
// Fused (4 rows per block): causal conv(K=4)+SiLU -> xact (bf16);
// headwise 4x4 q/k/v -> bf16 buffers; gate partials -> part[row][chunk][8].
__global__ __launch_bounds__(256) void conv_head_gate_kernel(
    const __hip_bfloat16* __restrict__ up, const float* __restrict__ cw,
    const float* __restrict__ cb,
    const float* __restrict__ wq, const float* __restrict__ wk,
    const float* __restrict__ wv,
    const float* __restrict__ igw, const float* __restrict__ fgw,
    __hip_bfloat16* __restrict__ xact,
    __hip_bfloat16* __restrict__ qb, __hip_bfloat16* __restrict__ kb,
    __hip_bfloat16* __restrict__ vb, float* __restrict__ part) {
  const int rblk  = blockIdx.x >> 3;       // 0..735 (4 rows each)
  const int chunk = blockIdx.x & 7;
  const int r0 = rblk * 4;
  const int t = threadIdx.x;
  const int c = chunk*256 + t;
  const int lane = t & 63, wv_ = t >> 6;
  const int gbl = lane & ~3;               // shuffle group base lane

  // per-channel weights (read once, used for 4 rows)
  const float4 cw4 = *(const float4*)(cw + (size_t)c*4);
  const float wtap[4] = {cw4.x, cw4.y, cw4.z, cw4.w};
  const float bias = cb[c];
  const int hq = c >> 2, o = c & 3;
  const size_t wo = ((size_t)hq*4 + o)*4;
  const float4 wq4 = *(const float4*)(wq + wo);
  const float4 wk4 = *(const float4*)(wk + wo);
  const float4 wv4 = *(const float4*)(wv + wo);
  const float wqv[4] = {wq4.x,wq4.y,wq4.z,wq4.w};
  const float wkv[4] = {wk4.x,wk4.y,wk4.z,wk4.w};
  const float wvv[4] = {wv4.x,wv4.y,wv4.z,wv4.w};
  const float4 wiq = *(const float4*)(igw + (size_t)c*4);
  const float4 wik = *(const float4*)(igw + (size_t)(2048+c)*4);
  const float4 wiv = *(const float4*)(igw + (size_t)(4096+c)*4);
  const float4 wfq = *(const float4*)(fgw + (size_t)c*4);
  const float4 wfk = *(const float4*)(fgw + (size_t)(2048+c)*4);
  const float4 wfv = *(const float4*)(fgw + (size_t)(4096+c)*4);

  // input rows r0-3 .. r0+3 (7 rows), bf16 scalar loads
  float u[7];
#pragma unroll
  for (int i = 0; i < 7; ++i) {
    const int gr = r0 - 3 + i;
    u[i] = (gr >= 0) ? bf2f(((const short*)up)[(size_t)gr*(2*SI) + c]) : 0.f;
  }

  __shared__ float red[4][4][8];   // [row][wave][gate]

  const int h = c >> 9, dd = c & 511;
#pragma unroll
  for (int rr = 0; rr < 4; ++rr) {
    const int row = r0 + rr;
    const int b = row / SS, s = row - (row / SS)*SS;
    // conv + SiLU
    float acc = bias;
#pragma unroll
    for (int j = 0; j < 4; ++j) {
      if (s - 3 + j >= 0) acc += u[rr + j] * wtap[j];
    }
    const float xa = acc / (1.f + expf(-acc));
    xact[(size_t)row*SI + c] = __float2bfloat16(xa);
    const float xin = u[rr + 3];
    // headwise via wave shuffles (4-lane groups, never cross wave)
    float q = 0.f, k = 0.f, v = 0.f;
#pragma unroll
    for (int d = 0; d < 4; ++d) {
      const float xad = __shfl(xa, gbl + d);
      const float xid = __shfl(xin, gbl + d);
      q += xad * wqv[d]; k += xad * wkv[d]; v += xid * wvv[d];
    }
    const size_t dst = (((size_t)b*NHH + h)*SS + s)*DHH + dd;
    qb[dst] = __float2bfloat16(q);
    kb[dst] = __float2bfloat16(k);
    vb[dst] = __float2bfloat16(v);
    // gate partials
    float a8[8];
    a8[0] = q*wiq.x + k*wik.x + v*wiv.x;
    a8[1] = q*wiq.y + k*wik.y + v*wiv.y;
    a8[2] = q*wiq.z + k*wik.z + v*wiv.z;
    a8[3] = q*wiq.w + k*wik.w + v*wiv.w;
    a8[4] = q*wfq.x + k*wfk.x + v*wfv.x;
    a8[5] = q*wfq.y + k*wfk.y + v*wfv.y;
    a8[6] = q*wfq.z + k*wfk.z + v*wfv.z;
    a8[7] = q*wfq.w + k*wfk.w + v*wfv.w;
    for (int off = 32; off; off >>= 1)
#pragma unroll
      for (int g = 0; g < 8; ++g) a8[g] += __shfl_down(a8[g], off);
    if (lane == 0)
#pragma unroll
      for (int g = 0; g < 8; ++g) red[rr][wv_][g] = a8[g];
  }
  __syncthreads();
  if (t < 32) {
    const int rr = t >> 3, g = t & 7;
    part[(size_t)(r0 + rr)*64 + chunk*8 + g] =
        red[rr][0][g] + red[rr][1][g] + red[rr][2][g] + red[rr][3][g];
  }
}

// ---------------------------------------------------------------------------
// mLSTM per (b,head): gate reduce + MFMA QK^T + VALU PV + fused multi-head
// norm/skip/gate epilogue -> habf bf16 [b*s][2048].
__global__ __launch_bounds__(256) void mlstm_mfma_kernel(
    const __hip_bfloat16* __restrict__ qb, const __hip_bfloat16* __restrict__ kb,
    const __hip_bfloat16* __restrict__ vb,
    const float* __restrict__ part,
    const float* __restrict__ igb, const float* __restrict__ fgb,
    const __hip_bfloat16* __restrict__ xact, const __hip_bfloat16* __restrict__ up,
    const float* __restrict__ skip, const float* __restrict__ mhn,
    __hip_bfloat16* __restrict__ habf) {
  const int bh = blockIdx.x;                 // b*4 + h
  const int b = bh >> 2, h = bh & 3;
  const int t = threadIdx.x;
  const int lane = t & 63, wid = t >> 6;
  const int l15 = lane & 15, lg = lane >> 4;

  __shared__ short QKs[2][48*264];
  __shared__ float Cs[46][48];
  __shared__ float cum[46], mmv[46], ips[46], fps[46], inv[46];
  short* Vs = &QKs[0][0];                    // alias: V [46][520] bf16

  if (t < SS) {
    const float* pr = part + (size_t)(b*SS + t)*64;
    float si = igb[h], sf = fgb[h];
#pragma unroll
    for (int ch = 0; ch < 8; ++ch) { si += pr[ch*8 + h]; sf += pr[ch*8 + 4 + h]; }
    ips[t] = si; fps[t] = sf;
  }

  int prs[3]; int np = 0;
  for (int p = wid; p < 9; p += 4) prs[np++] = p;
  f32x4 acc[3];
#pragma unroll
  for (int i = 0; i < 3; ++i) acc[i] = (f32x4){0.f,0.f,0.f,0.f};

  for (int ph = 0; ph < 2; ++ph) {
    __syncthreads();
    for (int i = t; i < 48*32; i += 256) {
      const int row = i >> 5, oc = i & 31;
      bf16x8 vq = {0,0,0,0,0,0,0,0}, vk = {0,0,0,0,0,0,0,0};
      if (row < SS) {
        const size_t src = ((size_t)bh*SS + row)*DHH + ph*256 + oc*8;
        vq = *(const bf16x8*)(qb + src);
        vk = *(const bf16x8*)(kb + src);
      }
      *(bf16x8*)&QKs[0][row*264 + oc*8] = vq;
      *(bf16x8*)&QKs[1][row*264 + oc*8] = vk;
    }
    __syncthreads();
#pragma unroll
    for (int kc = 0; kc < 8; ++kc) {
      for (int i = 0; i < np; ++i) {
        const int mt = prs[i] / 3, nt = prs[i] - 3*(prs[i]/3);
        const bf16x8 a = *(const bf16x8*)&QKs[0][(mt*16 + l15)*264 + kc*32 + lg*8];
        const bf16x8 bb = *(const bf16x8*)&QKs[1][(nt*16 + l15)*264 + kc*32 + lg*8];
        acc[i] = __builtin_amdgcn_mfma_f32_16x16x32_bf16(a, bb, acc[i], 0, 0, 0);
      }
    }
  }
  __syncthreads();
  if (t == 0) {
    float c = 0.f, rmax = -INFINITY;
    for (int s = 0; s < SS; ++s) {
      const float xv = fps[s];
      const float lf = fminf(xv, 0.f) - log1pf(expf(-fabsf(xv)));
      c += lf; cum[s] = c;
      rmax = fmaxf(rmax, ips[s] - c);
      mmv[s] = c + rmax;
    }
  }
  for (int i = t; i < SS*64; i += 256) {
    const int row = i >> 6, oc = i & 63;
    *(bf16x8*)&Vs[row*520 + oc*8] =
        *(const bf16x8*)(vb + ((size_t)bh*SS + row)*DHH + oc*8);
  }
  __syncthreads();
  const float rsq = 0.04419417382415922f;
  for (int i = 0; i < np; ++i) {
    const int mt = prs[i] / 3, nt = prs[i] - 3*(prs[i]/3);
    const int s = nt*16 + l15;
    if (s < SS) {
#pragma unroll
      for (int j = 0; j < 4; ++j) {
        const int tt = mt*16 + lg*4 + j;
        if (tt < SS) {
          float wgt = 0.f;
          if (s <= tt) wgt = rsq * expf(cum[tt] - cum[s] + ips[s] - mmv[tt]);
          Cs[tt][s] = acc[i][j] * wgt;
        }
      }
    }
  }
  __syncthreads();
  if (t < SS) {
    float ssum = 0.f;
    for (int s = 0; s <= t; ++s) ssum += Cs[t][s];
    inv[t] = 1.f / (fmaxf(fabsf(ssum), expf(-mmv[t])) + 1e-6f);
  }
  __syncthreads();
  // PV + fused mhnorm/skip/gate epilogue
  const int c0 = h*DHH + lane*8;
  for (int it = 0; it < 12; ++it) {
    const int tt = wid + it*4;
    if (tt >= SS) break;
    float a[8];
#pragma unroll
    for (int j = 0; j < 8; ++j) a[j] = 0.f;
    for (int s = 0; s <= tt; ++s) {
      const float c = Cs[tt][s];
      const bf16x8 v8 = *(const bf16x8*)&Vs[s*520 + lane*8];
#pragma unroll
      for (int j = 0; j < 8; ++j) a[j] += c * bf2f(v8[j]);
    }
    const float sc = inv[tt];
    float s1 = 0.f, s2 = 0.f;
#pragma unroll
    for (int j = 0; j < 8; ++j) { a[j] *= sc; s1 += a[j]; s2 += a[j]*a[j]; }
#pragma unroll
    for (int off = 1; off < 64; off <<= 1) {
      s1 += __shfl_xor(s1, off); s2 += __shfl_xor(s2, off);
    }
    const float mu = s1 * (1.f/512.f);
    const float var = s2 * (1.f/512.f) - mu*mu;
    const float rs = rsqrtf(var + 1e-5f);
    const int row = b*SS + tt;
    const bf16x8 xa8 = *(const bf16x8*)((const short*)xact + (size_t)row*SI + c0);
    const bf16x8 z8 = *(const bf16x8*)((const short*)up + (size_t)row*(2*SI) + SI + c0);
    const float4 mh0 = *(const float4*)(mhn + c0);
    const float4 mh1 = *(const float4*)(mhn + c0 + 4);
    const float4 sk0 = *(const float4*)(skip + c0);
    const float4 sk1 = *(const float4*)(skip + c0 + 4);
    const float mhv[8] = {mh0.x,mh0.y,mh0.z,mh0.w,mh1.x,mh1.y,mh1.z,mh1.w};
    const float skv[8] = {sk0.x,sk0.y,sk0.z,sk0.w,sk1.x,sk1.y,sk1.z,sk1.w};
    bf16x8 o8;
#pragma unroll
    for (int j = 0; j < 8; ++j) {
      const float hv = (a[j]-mu)*rs*mhv[j] + skv[j]*bf2f(xa8[j]);
      const float zv = bf2f(z8[j]);
      const float r = hv * (zv / (1.f + expf(-zv)));
      union { float f; unsigned int u; } cv; cv.f = r;
      unsigned int lsb = (cv.u >> 16) & 1;
      cv.u += 0x7fff + lsb;
      o8[j] = (short)(cv.u >> 16);
    }
    *(bf16x8*)((short*)habf + (size_t)row*SI + c0) = o8;
  }
}

// ---------------------------------------------------------------------------
// Final projection: grid 512 = (b, o-chunk of 64); 4 waves split K.
__global__ __launch_bounds__(256) void proj2_kernel(
    const float* __restrict__ lastln, const float* __restrict__ pw,
    const float* __restrict__ pb, float* __restrict__ out) {
  const int b = blockIdx.x >> 3;
  const int och = blockIdx.x & 7;
  const int t = threadIdx.x;
  const int w = t >> 6, lane = t & 63;
  __shared__ float xs[SE];
  __shared__ float red[4][64];
  for (int i = t; i < SE; i += 256) xs[i] = lastln[(size_t)b*SE + i];
  __syncthreads();
  const int o = och*64 + lane;
  float acc = 0.f;
  const int kbeg = w*256;
#pragma unroll 8
  for (int k = kbeg; k < kbeg + 256; ++k)
    acc += xs[k] * pw[(size_t)k*OUTD + o];
  red[w][lane] = acc;
  __syncthreads();
  if (t < 64)
    out[(size_t)b*OUTD + och*64 + t] =
        red[0][t] + red[1][t] + red[2][t] + red[3][t] + pb[och*64 + t];
}

// ---------------------------------------------------------------------------
extern "C" void kernel_launch(void* const* d_in, const int* in_sizes, int n_in,
                              void* d_out, int out_size, void* d_ws, size_t ws_size,
                              hipStream_t stream) {
  const float* x_in   = (const float*)d_in[0];
  const float* ln_w   = (const float*)d_in[1];
  const float* w_up   = (const float*)d_in[2];
  const float* conv_w = (const float*)d_in[3];
  const float* conv_b = (const float*)d_in[4];
  const float* wq     = (const float*)d_in[5];
  const float* wk     = (const float*)d_in[6];
  const float* wv     = (const float*)d_in[7];
  const float* ig_w   = (const float*)d_in[8];
  const float* ig_b   = (const float*)d_in[9];
  const float* fg_w   = (const float*)d_in[10];
  const float* fg_b   = (const float*)d_in[11];
  const float* skip   = (const float*)d_in[12];
  const float* mhn_w  = (const float*)d_in[13];
  const float* w_down = (const float*)d_in[14];
  const float* post_w = (const float*)d_in[15];
  const float* proj_w = (const float*)d_in[16];
  const float* proj_b = (const float*)d_in[17];
  float* out = (float*)d_out;

  float* ws = (float*)d_ws;
  float* xbuf   = ws;                                   // ROWS*SE
  float* part   = xbuf  + (size_t)ROWS*SE;              // ROWS*64
  float* lastln = part  + (size_t)ROWS*64;              // SB*SE
  float* cpart  = lastln + (size_t)SB*SE;               // KSPLIT * ROWS*SE
  __hip_bfloat16* lnb   = (__hip_bfloat16*)(cpart + (size_t)KSPLIT*ROWS*SE);
  __hip_bfloat16* upbuf = lnb   + (size_t)ROWS*SE;      // ROWS*2*SI bf16
  __hip_bfloat16* xact  = upbuf + (size_t)ROWS*2*SI;    // ROWS*SI bf16
  __hip_bfloat16* qb    = xact  + (size_t)ROWS*SI;      // ROWS*SI [b][h][s][d]
  __hip_bfloat16* kb    = qb    + (size_t)ROWS*SI;
  __hip_bfloat16* vb    = kb    + (size_t)ROWS*SI;
  __hip_bfloat16* habf  = vb    + (size_t)ROWS*SI;      // ROWS*SI
  __hip_bfloat16* wTup  = habf  + (size_t)ROWS*SI;      // 8 * 4096*1024
  __hip_bfloat16* wTdn  = wTup  + (size_t)8*SE*2*SI;    // 8 * 1024*2048

  hipMemcpyAsync(xbuf, x_in, (size_t)ROWS*SE*sizeof(float),
                 hipMemcpyDeviceToDevice, stream);

  // hoisted weight transposes (all 8 layers)
  transpose_bf16_kernel<<<dim3(128, 32, 8), 256, 0, stream>>>(w_up, wTup, SE, 2*SI);
  transpose_bf16_kernel<<<dim3(32, 64, 8), 256, 0, stream>>>(w_down, wTdn, SI, SE);

  for (int blk = 0; blk < 8; ++blk) {
    const float* lw   = ln_w   + (size_t)blk*SE;
    const float* cw   = conv_w + (size_t)blk*SI*4;
    const float* cb   = conv_b + (size_t)blk*SI;
    const float* wqb  = wq     + (size_t)blk*NHQ_*16;
    const float* wkb  = wk     + (size_t)blk*NHQ_*16;
    const float* wvb  = wv     + (size_t)blk*NHQ_*16;
    const float* igwb = ig_w   + (size_t)blk*3*SI*NHH;
    const float* igbb = ig_b   + (size_t)blk*NHH;
    const float* fgwb = fg_w   + (size_t)blk*3*SI*NHH;
    const float* fgbb = fg_b   + (size_t)blk*NHH;
    const float* skb  = skip   + (size_t)blk*SI;
    const float* mhb  = mhn_w  + (size_t)blk*SI;

    // residual-add (prev layer's split-K parts) + LN -> bf16
    lnres_bf16_kernel<<<ROWS, 256, 0, stream>>>(
        xbuf, cpart, blk == 0 ? 0 : KSPLIT, lw, lnb);
    gemm_mfma<<<dim3(32, 23, 1), 256, 0, stream>>>(
        lnb, SE, wTup + (size_t)blk*SE*2*SI, SE, upbuf, 2*SI, SE, 0, 2);
    conv_head_gate_kernel<<<(ROWS/4)*8, 256, 0, stream>>>(
        upbuf, cw, cb, wqb, wkb, wvb, igwb, fgwb, xact, qb, kb, vb, part);
    mlstm_mfma_kernel<<<SB*NHH, 256, 0, stream>>>(
        qb, kb, vb, part, igbb, fgbb, xact, upbuf, skb, mhb, habf);
    gemm_mfma<<<dim3(8, 23, KSPLIT), 256, 0, stream>>>(
        habf, SI, wTdn + (size_t)blk*SI*SE, SI, cpart, SE, SI, (size_t)ROWS*SE, 0);
  }
  ln_last_kernel<<<SB, 256, 0, stream>>>(xbuf, cpart, KSPLIT, post_w, lastln);
  proj2_kernel<<<SB*8, 256, 0, stream>>>(lastln, proj_w, proj_b, out);
}